// Round 1
// baseline (4992.171 us; speedup 1.0000x reference)
//
#include <hip/hip_runtime.h>
#include <hip/hip_bf16.h>
#include <math.h>

// Problem constants
#define BB 4
#define SS 2048
#define EE 1024
#define HH 16
#define DD 64
#define FF 4096

static __device__ __forceinline__ float gelu_exact(float v){
  return 0.5f * v * (1.0f + erff(v * 0.70710678118654752f));
}

// ---------------- embedding gather ----------------
__global__ __launch_bounds__(256) void embed_kernel(const int* __restrict__ ids,
    const float* __restrict__ emb, float* __restrict__ x){
  int row = blockIdx.x;
  int id  = ids[row];
  const float4* src = (const float4*)(emb + (size_t)id * EE);
  float4* dst = (float4*)(x + (size_t)row * EE);
  dst[threadIdx.x] = src[threadIdx.x];
}

// ---------------- f32 GEMM: C[M,N] = A[M,K] @ W[K,N] + bias ----------------
// MODE 0: write C.  MODE 1: gelu + per-batch column-sum atomically into C[B,N].
template<int MODE>
__global__ __launch_bounds__(256) void gemm128(const float* __restrict__ A,
    const float* __restrict__ W, const float* __restrict__ bias,
    float* __restrict__ C, int M, int N, int K){
  __shared__ float As[16][128];
  __shared__ float Ws[16][128];
  const int tid = threadIdx.x;
  const int tx = tid & 15, ty = tid >> 4;
  const int r0 = blockIdx.y * 128;
  const int c0 = blockIdx.x * 128;

  float acc[8][8];
  #pragma unroll
  for (int i=0;i<8;i++)
    #pragma unroll
    for (int j=0;j<8;j++) acc[i][j]=0.f;

  const int am = tid >> 1;         // A row 0..127
  const int ah = (tid & 1) * 8;    // A k-offset 0 or 8
  const int wk = tid >> 4;         // W k-row 0..15
  const int wn = (tid & 15) * 8;   // W col offset
  const float* Ap = A + (size_t)(r0 + am) * K + ah;
  const float* Wpp = W + (size_t)wk * N + c0 + wn;

  for (int k0 = 0; k0 < K; k0 += 16){
    float4 a0 = *(const float4*)(Ap);
    float4 a1 = *(const float4*)(Ap + 4);
    float4 w0 = *(const float4*)(Wpp);
    float4 w1 = *(const float4*)(Wpp + 4);
    As[ah+0][am]=a0.x; As[ah+1][am]=a0.y; As[ah+2][am]=a0.z; As[ah+3][am]=a0.w;
    As[ah+4][am]=a1.x; As[ah+5][am]=a1.y; As[ah+6][am]=a1.z; As[ah+7][am]=a1.w;
    *(float4*)&Ws[wk][wn]   = w0;
    *(float4*)&Ws[wk][wn+4] = w1;
    __syncthreads();
    #pragma unroll
    for (int kk=0;kk<16;kk++){
      float4 xa0 = *(float4*)&As[kk][ty*8];
      float4 xa1 = *(float4*)&As[kk][ty*8+4];
      float4 yb0 = *(float4*)&Ws[kk][tx*8];
      float4 yb1 = *(float4*)&Ws[kk][tx*8+4];
      float av[8] = {xa0.x,xa0.y,xa0.z,xa0.w,xa1.x,xa1.y,xa1.z,xa1.w};
      float bv[8] = {yb0.x,yb0.y,yb0.z,yb0.w,yb1.x,yb1.y,yb1.z,yb1.w};
      #pragma unroll
      for (int i=0;i<8;i++)
        #pragma unroll
        for (int j=0;j<8;j++) acc[i][j] += av[i]*bv[j];
    }
    __syncthreads();
    Ap += 16;
    Wpp += (size_t)16 * N;
  }

  float bl[8];
  #pragma unroll
  for (int j=0;j<8;j++) bl[j] = bias[c0 + tx*8 + j];

  if constexpr (MODE == 0){
    #pragma unroll
    for (int i=0;i<8;i++){
      int row = r0 + ty*8 + i;
      float4 o0 = make_float4(acc[i][0]+bl[0], acc[i][1]+bl[1], acc[i][2]+bl[2], acc[i][3]+bl[3]);
      float4 o1 = make_float4(acc[i][4]+bl[4], acc[i][5]+bl[5], acc[i][6]+bl[6], acc[i][7]+bl[7]);
      float4* dst = (float4*)(C + (size_t)row * N + c0 + tx*8);
      dst[0] = o0; dst[1] = o1;
    }
  } else {
    __shared__ float red[16][128];
    float cs[8];
    #pragma unroll
    for (int j=0;j<8;j++) cs[j]=0.f;
    #pragma unroll
    for (int i=0;i<8;i++)
      #pragma unroll
      for (int j=0;j<8;j++) cs[j] += gelu_exact(acc[i][j] + bl[j]);
    #pragma unroll
    for (int j=0;j<8;j++) red[ty][tx*8+j] = cs[j];
    __syncthreads();
    if (tid < 128){
      float ssum = 0.f;
      #pragma unroll
      for (int t2=0;t2<16;t2++) ssum += red[t2][tid];
      int batch = r0 >> 11;   // r0 / 2048
      atomicAdd(&C[(size_t)batch * N + c0 + tid], ssum);
    }
  }
}

// ---------------- flash attention, f32, 16 q-rows per block ----------------
__global__ __launch_bounds__(256) void attn_kernel(const float* __restrict__ q,
    const float* __restrict__ k, const float* __restrict__ v,
    const int* __restrict__ mask, float* __restrict__ ctx){
  const int bh = blockIdx.y;
  const int b = bh >> 4, h = bh & 15;
  const int q0 = blockIdx.x * 16;
  const int tid = threadIdx.x;

  __shared__ float Qt[16][68];
  __shared__ float Kt[64][68];
  __shared__ float Vt[64][68];
  __shared__ float Pt[16][68];

  { // load Q tile (16 rows x 64)
    int row = tid >> 4, dq = (tid & 15) * 4;
    const float* src = q + ((size_t)(b*SS + q0 + row)) * EE + h*DD + dq;
    *(float4*)&Qt[row][dq] = *(const float4*)src;
  }

  const int srow = tid >> 4;        // row 0..15 (score & PV phases)
  const int kc   = tid & 15;        // key-chunk in score phase
  const int dc   = (tid & 15) * 4;  // d-chunk in PV phase
  float m_run = -1e30f, l_run = 0.f;
  float4 o = make_float4(0.f,0.f,0.f,0.f);
  __syncthreads();

  for (int t0 = 0; t0 < SS; t0 += 64){
    { // stage K,V tile (64 keys x 64 d)
      int j = tid >> 2, cq = (tid & 3) * 16;
      const float* ksrc = k + ((size_t)(b*SS + t0 + j)) * EE + h*DD + cq;
      const float* vsrc = v + ((size_t)(b*SS + t0 + j)) * EE + h*DD + cq;
      #pragma unroll
      for (int i=0;i<4;i++){
        *(float4*)&Kt[j][cq + 4*i] = ((const float4*)ksrc)[i];
        *(float4*)&Vt[j][cq + 4*i] = ((const float4*)vsrc)[i];
      }
    }
    __syncthreads();

    // scores: thread (srow, kc) computes 4 keys
    float s[4] = {0.f,0.f,0.f,0.f};
    const int kbase = kc * 4;
    #pragma unroll
    for (int d4=0; d4<16; d4++){
      float4 qv = *(float4*)&Qt[srow][d4*4];
      #pragma unroll
      for (int jj=0;jj<4;jj++){
        float4 kv = *(float4*)&Kt[kbase+jj][d4*4];
        s[jj] += qv.x*kv.x + qv.y*kv.y + qv.z*kv.z + qv.w*kv.w;
      }
    }
    #pragma unroll
    for (int jj=0;jj<4;jj++){
      int mk = mask[b*SS + t0 + kbase + jj];
      s[jj] = (mk != 0) ? s[jj] * 0.125f : -1e30f;
    }
    // row-wise online softmax (16 lanes per row)
    float mloc = fmaxf(fmaxf(s[0],s[1]), fmaxf(s[2],s[3]));
    #pragma unroll
    for (int off=8; off; off>>=1) mloc = fmaxf(mloc, __shfl_xor(mloc, off, 16));
    float m_new = fmaxf(m_run, mloc);
    float alpha = __expf(m_run - m_new);
    float p[4];
    float lloc = 0.f;
    #pragma unroll
    for (int jj=0;jj<4;jj++){ p[jj] = __expf(s[jj] - m_new); lloc += p[jj]; }
    #pragma unroll
    for (int off=8; off; off>>=1) lloc += __shfl_xor(lloc, off, 16);
    l_run = l_run * alpha + lloc;
    m_run = m_new;
    *(float4*)&Pt[srow][kc*4] = make_float4(p[0],p[1],p[2],p[3]);
    __syncthreads();

    // PV: thread (srow, dc) accumulates o[srow][dc..dc+3]
    o.x *= alpha; o.y *= alpha; o.z *= alpha; o.w *= alpha;
    #pragma unroll
    for (int j4=0;j4<16;j4++){
      float4 pv = *(float4*)&Pt[srow][j4*4];
      float pa[4] = {pv.x, pv.y, pv.z, pv.w};
      #pragma unroll
      for (int jj=0;jj<4;jj++){
        float4 vv = *(float4*)&Vt[j4*4+jj][dc];
        o.x += pa[jj]*vv.x; o.y += pa[jj]*vv.y; o.z += pa[jj]*vv.z; o.w += pa[jj]*vv.w;
      }
    }
    __syncthreads();
  }

  float inv_l = 1.f / l_run;
  o.x *= inv_l; o.y *= inv_l; o.z *= inv_l; o.w *= inv_l;
  float* dst = ctx + ((size_t)(b*SS + q0 + srow)) * EE + h*DD + dc;
  *(float4*)dst = o;
}

// ---------------- fused residual + LayerNorm ----------------
__global__ __launch_bounds__(256) void ln_kernel(const float* __restrict__ ctx2,
    const float* __restrict__ x, const float* __restrict__ g,
    const float* __restrict__ bta, float* __restrict__ h){
  int row = blockIdx.x, tid = threadIdx.x;
  const float4* a  = (const float4*)(ctx2 + (size_t)row * EE);
  const float4* xr = (const float4*)(x    + (size_t)row * EE);
  float4 av = a[tid], xv = xr[tid];
  float4 y = make_float4(av.x+xv.x, av.y+xv.y, av.z+xv.z, av.w+xv.w);
  float s  = y.x + y.y + y.z + y.w;
  float ss = y.x*y.x + y.y*y.y + y.z*y.z + y.w*y.w;
  #pragma unroll
  for (int off=32; off; off>>=1){
    s  += __shfl_xor(s,  off, 64);
    ss += __shfl_xor(ss, off, 64);
  }
  __shared__ float rs[4], rss[4];
  int w = tid >> 6;
  if ((tid & 63) == 0){ rs[w] = s; rss[w] = ss; }
  __syncthreads();
  float tot  = rs[0]+rs[1]+rs[2]+rs[3];
  float tots = rss[0]+rss[1]+rss[2]+rss[3];
  float mu  = tot  * (1.f/EE);
  float var = tots * (1.f/EE) - mu*mu;
  float inv = rsqrtf(var + 1e-5f);
  float4 gv = ((const float4*)g)[tid];
  float4 bv = ((const float4*)bta)[tid];
  float4 out = make_float4((y.x-mu)*inv*gv.x + bv.x,
                           (y.y-mu)*inv*gv.y + bv.y,
                           (y.z-mu)*inv*gv.z + bv.z,
                           (y.w-mu)*inv*gv.w + bv.w);
  ((float4*)(h + (size_t)row * EE))[tid] = out;
}

// ---------------- t[b,e] = (gsum[b,:]/S) @ W2[:,e] + b2[e] ----------------
__global__ __launch_bounds__(256) void w2_kernel(const float* __restrict__ gsum,
    const float* __restrict__ W2, const float* __restrict__ b2, float* __restrict__ t){
  int idx = blockIdx.x * 256 + threadIdx.x;   // 0..4095
  int b = idx >> 10, e = idx & 1023;
  float acc = 0.f;
  #pragma unroll 8
  for (int f=0; f<FF; f++) acc += gsum[b*FF + f] * W2[(size_t)f * EE + e];
  t[idx] = acc * (1.f/SS) + b2[e];
}

// ---------------- out[b,j] = t[b,:] @ Wp[:,j] + bp[j] ----------------
__global__ __launch_bounds__(256) void out_kernel(const float* __restrict__ t,
    const float* __restrict__ Wp, const float* __restrict__ bp, float* __restrict__ out){
  int tid = threadIdx.x;
  float part[4][3];
  #pragma unroll
  for (int b=0;b<4;b++) for (int j=0;j<3;j++) part[b][j]=0.f;
  int e0 = tid * 4;
  #pragma unroll
  for (int b=0;b<4;b++){
    float4 tv = *(const float4*)&t[b*EE + e0];
    float ta[4] = {tv.x,tv.y,tv.z,tv.w};
    #pragma unroll
    for (int i=0;i<4;i++){
      int e = e0 + i;
      part[b][0] += ta[i] * Wp[e*3+0];
      part[b][1] += ta[i] * Wp[e*3+1];
      part[b][2] += ta[i] * Wp[e*3+2];
    }
  }
  __shared__ float red[12][4];
  int lane = tid & 63, w = tid >> 6;
  #pragma unroll
  for (int b=0;b<4;b++){
    #pragma unroll
    for (int j=0;j<3;j++){
      float vsum = part[b][j];
      #pragma unroll
      for (int off=32; off; off>>=1) vsum += __shfl_xor(vsum, off, 64);
      if (lane == 0) red[b*3+j][w] = vsum;
    }
  }
  __syncthreads();
  if (tid < 12){
    float ssum = red[tid][0]+red[tid][1]+red[tid][2]+red[tid][3];
    out[tid] = ssum + bp[tid % 3];
  }
}

extern "C" void kernel_launch(void* const* d_in, const int* in_sizes, int n_in,
                              void* d_out, int out_size, void* d_ws, size_t ws_size,
                              hipStream_t stream) {
  const int M = BB * SS;                      // 8192
  const int* ids  = (const int*)d_in[0];
  const int* mask = (const int*)d_in[1];
  const float* emb = (const float*)d_in[2];
  const float* Wq = (const float*)d_in[3];  const float* bq = (const float*)d_in[4];
  const float* Wk = (const float*)d_in[5];  const float* bk = (const float*)d_in[6];
  const float* Wv = (const float*)d_in[7];  const float* bv = (const float*)d_in[8];
  const float* Wo = (const float*)d_in[9];  const float* bo = (const float*)d_in[10];
  const float* lg = (const float*)d_in[11]; const float* lb = (const float*)d_in[12];
  const float* W1 = (const float*)d_in[13]; const float* b1 = (const float*)d_in[14];
  const float* W2 = (const float*)d_in[15]; const float* b2 = (const float*)d_in[16];
  const float* Wp = (const float*)d_in[17]; const float* bp = (const float*)d_in[18];

  float* ws = (float*)d_ws;
  const size_t SLOT = (size_t)M * EE;         // 8.39M floats
  float* xf   = ws + 0*SLOT;
  float* qf   = ws + 1*SLOT;
  float* kf   = ws + 2*SLOT;
  float* vf   = ws + 3*SLOT;
  float* ctx  = ws + 4*SLOT;
  float* ctx2 = qf;                           // q dead after attention
  float* hbuf = kf;                           // k dead after attention
  float* gsum = ws + 5*SLOT;                  // B*F floats
  float* tbuf = gsum + BB*FF;                 // B*E floats

  hipMemsetAsync(gsum, 0, BB*FF*sizeof(float), stream);

  embed_kernel<<<M, 256, 0, stream>>>(ids, emb, xf);

  dim3 gQ(EE/128, M/128);
  gemm128<0><<<gQ, 256, 0, stream>>>(xf, Wq, bq, qf, M, EE, EE);
  gemm128<0><<<gQ, 256, 0, stream>>>(xf, Wk, bk, kf, M, EE, EE);
  gemm128<0><<<gQ, 256, 0, stream>>>(xf, Wv, bv, vf, M, EE, EE);

  attn_kernel<<<dim3(SS/16, BB*HH), 256, 0, stream>>>(qf, kf, vf, mask, ctx);

  gemm128<0><<<gQ, 256, 0, stream>>>(ctx, Wo, bo, ctx2, M, EE, EE);

  ln_kernel<<<M, 256, 0, stream>>>(ctx2, xf, lg, lb, hbuf);

  gemm128<1><<<dim3(FF/128, M/128), 256, 0, stream>>>(hbuf, W1, b1, gsum, M, FF, EE);

  w2_kernel<<<16, 256, 0, stream>>>(gsum, W2, b2, tbuf);
  out_kernel<<<1, 256, 0, stream>>>(tbuf, Wp, bp, (float*)d_out);
}

// Round 2
// 2781.592 us; speedup vs baseline: 1.7947x; 1.7947x over previous
//
#include <hip/hip_runtime.h>
#include <hip/hip_bf16.h>
#include <math.h>

// Problem constants
#define BB 4
#define SS 2048
#define EE 1024
#define HH 16
#define DD 64
#define FF 4096

typedef unsigned short u16;
typedef unsigned int u32;
typedef __bf16 bf16x8 __attribute__((ext_vector_type(8)));
typedef float f32x4 __attribute__((ext_vector_type(4)));

static __device__ __forceinline__ float gelu_exact(float v){
  return 0.5f * v * (1.0f + erff(v * 0.70710678118654752f));
}

// float -> bf16 (RNE)
static __device__ __forceinline__ u16 f2bf(float f){
  union { float f; u32 u; } x; x.f = f;
  u32 r = x.u + 0x7FFFu + ((x.u >> 16) & 1u);
  return (u16)(r >> 16);
}
// unpack a u32 holding two bf16 (little-endian: elem0 = low half)
static __device__ __forceinline__ void unpack2(u32 u, float& lo, float& hi){
  union { u32 u; float f; } a, b;
  a.u = u << 16; b.u = u & 0xFFFF0000u;
  lo = a.f; hi = b.f;
}

#define GLOAD_LDS16(g, l) \
  __builtin_amdgcn_global_load_lds((const __attribute__((address_space(1))) void*)(g), \
      (__attribute__((address_space(3))) void*)(l), 16, 0, 0)

// ---------------- embedding gather: write f32 (for residual) + bf16 (GEMM A) ----------------
__global__ __launch_bounds__(256) void embed_kernel(const int* __restrict__ ids,
    const float* __restrict__ emb, float* __restrict__ xf, u16* __restrict__ xbf){
  int row = blockIdx.x;
  int id  = ids[row];
  float4 v = ((const float4*)(emb + (size_t)id * EE))[threadIdx.x];
  ((float4*)(xf + (size_t)row * EE))[threadIdx.x] = v;
  ushort4 u; u.x = f2bf(v.x); u.y = f2bf(v.y); u.z = f2bf(v.z); u.w = f2bf(v.w);
  ((ushort4*)(xbf + (size_t)row * EE))[threadIdx.x] = u;
}

// ---------------- weight transpose + f32->bf16: WT[n][k] = W[k][n] ----------------
__global__ __launch_bounds__(256) void transpose_bf16(const float* __restrict__ W,
    u16* __restrict__ WT, int K, int N){
  __shared__ float tile[32][33];
  int n0 = blockIdx.x * 32, k0 = blockIdx.y * 32;
  int tx = threadIdx.x & 31, ty = threadIdx.x >> 5;   // ty 0..7
  #pragma unroll
  for (int i = 0; i < 4; i++)
    tile[ty + 8*i][tx] = W[(size_t)(k0 + ty + 8*i) * N + n0 + tx];
  __syncthreads();
  #pragma unroll
  for (int i = 0; i < 4; i++)
    WT[(size_t)(n0 + ty + 8*i) * K + k0 + tx] = f2bf(tile[tx][ty + 8*i]);
}

// ---------------- bf16 MFMA GEMM: C[M,N] = A[M,K] @ W[K,N] + bias ----------------
// A: bf16 row-major [M,K]. WT: bf16 [N,K] (W transposed). 128x128 tile, BK=32.
// MODE 0: store bf16 C.  MODE 1: gelu + per-batch column-sum atomics into gsum[B][N].
template<int MODE>
__global__ __launch_bounds__(256) void gemm_mfma(const u16* __restrict__ A,
    const u16* __restrict__ WT, const float* __restrict__ bias,
    u16* __restrict__ C, float* __restrict__ gsum, int M, int N, int K){
  __shared__ __attribute__((aligned(16))) u16 As[128 * 32];   // [row][k] 8 KB
  __shared__ __attribute__((aligned(16))) u16 Bs[128 * 32];   // [n][k]   8 KB

  const int tid = threadIdx.x;
  const int l = tid & 63, w = tid >> 6;
  const int lm = l & 15, lq = l >> 4;
  const int wm = (w >> 1) * 64, wn = (w & 1) * 64;
  const int r0 = blockIdx.y * 128, c0 = blockIdx.x * 128;

  // staging coords: wave w issues instrs t=w*2, w*2+1 for each of A and B.
  // instr t covers LDS rows t*16..t*16+15 (64 B per row, 4 lanes/row).
  const int srow0 = w * 32 + (l >> 2);          // row for instr 0 (t = w*2)
  const int scol  = (l & 3) * 8;                // k-element offset within row
  const u16* Ab = A  + (size_t)(r0 + srow0) * K + scol;
  const u16* Bb = WT + (size_t)(c0 + srow0) * K + scol;
  u16* AsBase0 = &As[(w * 2)     * 512];
  u16* AsBase1 = &As[(w * 2 + 1) * 512];
  u16* BsBase0 = &Bs[(w * 2)     * 512];
  u16* BsBase1 = &Bs[(w * 2 + 1) * 512];

  f32x4 acc[4][4];
  const f32x4 zero = {0.f, 0.f, 0.f, 0.f};
  #pragma unroll
  for (int mi = 0; mi < 4; mi++)
    #pragma unroll
    for (int ni = 0; ni < 4; ni++) acc[mi][ni] = zero;

  for (int k0 = 0; k0 < K; k0 += 32){
    GLOAD_LDS16(Ab + k0,                    AsBase0);
    GLOAD_LDS16(Ab + (size_t)16 * K + k0,   AsBase1);
    GLOAD_LDS16(Bb + k0,                    BsBase0);
    GLOAD_LDS16(Bb + (size_t)16 * K + k0,   BsBase1);
    __syncthreads();

    bf16x8 af[4], bf[4];
    #pragma unroll
    for (int mi = 0; mi < 4; mi++)
      af[mi] = *(const bf16x8*)&As[(wm + mi*16 + lm) * 32 + lq * 8];
    #pragma unroll
    for (int ni = 0; ni < 4; ni++)
      bf[ni] = *(const bf16x8*)&Bs[(wn + ni*16 + lm) * 32 + lq * 8];
    #pragma unroll
    for (int mi = 0; mi < 4; mi++)
      #pragma unroll
      for (int ni = 0; ni < 4; ni++)
        acc[mi][ni] = __builtin_amdgcn_mfma_f32_16x16x32_bf16(af[mi], bf[ni], acc[mi][ni], 0, 0, 0);
    __syncthreads();
  }

  // C/D layout (verified m89/m91): col = lane&15, row = (lane>>4)*4 + reg
  if constexpr (MODE == 0){
    #pragma unroll
    for (int ni = 0; ni < 4; ni++){
      int col = c0 + wn + ni*16 + lm;
      float bcol = bias[col];
      #pragma unroll
      for (int mi = 0; mi < 4; mi++){
        #pragma unroll
        for (int r = 0; r < 4; r++){
          int row = r0 + wm + mi*16 + lq*4 + r;
          C[(size_t)row * N + col] = f2bf(acc[mi][ni][r] + bcol);
        }
      }
    }
  } else {
    const int batch = r0 >> 11;   // 2048 rows per batch, 128 | 2048
    #pragma unroll
    for (int ni = 0; ni < 4; ni++){
      int col = c0 + wn + ni*16 + lm;
      float bcol = bias[col];
      float cs = 0.f;
      #pragma unroll
      for (int mi = 0; mi < 4; mi++)
        #pragma unroll
        for (int r = 0; r < 4; r++)
          cs += gelu_exact(acc[mi][ni][r] + bcol);
      cs += __shfl_xor(cs, 16, 64);
      cs += __shfl_xor(cs, 32, 64);
      if (lq == 0) atomicAdd(&gsum[(size_t)batch * N + col], cs);
    }
  }
}

// ---------------- flash attention, f32 math, bf16 I/O, 16 q-rows per block ----------------
__global__ __launch_bounds__(256) void attn_kernel(const u16* __restrict__ q,
    const u16* __restrict__ k, const u16* __restrict__ v,
    const int* __restrict__ mask, u16* __restrict__ ctx){
  const int bh = blockIdx.y;
  const int b = bh >> 4, h = bh & 15;
  const int q0 = blockIdx.x * 16;
  const int tid = threadIdx.x;

  __shared__ float Qt[16][68];
  __shared__ float Kt[64][68];
  __shared__ float Vt[64][68];
  __shared__ float Pt[16][68];

  { // load Q tile (16 rows x 64), bf16 -> f32
    int row = tid >> 4, dq = (tid & 15) * 4;
    const u16* src = q + ((size_t)(b*SS + q0 + row)) * EE + h*DD + dq;
    uint2 qu = *(const uint2*)src;
    float f0,f1,f2,f3;
    unpack2(qu.x, f0, f1); unpack2(qu.y, f2, f3);
    Qt[row][dq+0]=f0; Qt[row][dq+1]=f1; Qt[row][dq+2]=f2; Qt[row][dq+3]=f3;
  }

  const int srow = tid >> 4;        // row 0..15
  const int kc   = tid & 15;        // key lane in score phase (keys kc+16*jj)
  const int dc   = (tid & 15) * 4;  // d-chunk in PV phase
  float m_run = -1e30f, l_run = 0.f;
  float4 o = make_float4(0.f,0.f,0.f,0.f);
  __syncthreads();

  for (int t0 = 0; t0 < SS; t0 += 64){
    { // stage K,V tile (64 keys x 64 d), bf16 -> f32
      int j = tid >> 2, cq = (tid & 3) * 16;
      const u16* ksrc = k + ((size_t)(b*SS + t0 + j)) * EE + h*DD + cq;
      const u16* vsrc = v + ((size_t)(b*SS + t0 + j)) * EE + h*DD + cq;
      uint4 ku0 = *(const uint4*)ksrc;
      uint4 ku1 = *(const uint4*)(ksrc + 8);
      uint4 vu0 = *(const uint4*)vsrc;
      uint4 vu1 = *(const uint4*)(vsrc + 8);
      float a0,a1;
      unpack2(ku0.x,a0,a1); Kt[j][cq+ 0]=a0; Kt[j][cq+ 1]=a1;
      unpack2(ku0.y,a0,a1); Kt[j][cq+ 2]=a0; Kt[j][cq+ 3]=a1;
      unpack2(ku0.z,a0,a1); Kt[j][cq+ 4]=a0; Kt[j][cq+ 5]=a1;
      unpack2(ku0.w,a0,a1); Kt[j][cq+ 6]=a0; Kt[j][cq+ 7]=a1;
      unpack2(ku1.x,a0,a1); Kt[j][cq+ 8]=a0; Kt[j][cq+ 9]=a1;
      unpack2(ku1.y,a0,a1); Kt[j][cq+10]=a0; Kt[j][cq+11]=a1;
      unpack2(ku1.z,a0,a1); Kt[j][cq+12]=a0; Kt[j][cq+13]=a1;
      unpack2(ku1.w,a0,a1); Kt[j][cq+14]=a0; Kt[j][cq+15]=a1;
      unpack2(vu0.x,a0,a1); Vt[j][cq+ 0]=a0; Vt[j][cq+ 1]=a1;
      unpack2(vu0.y,a0,a1); Vt[j][cq+ 2]=a0; Vt[j][cq+ 3]=a1;
      unpack2(vu0.z,a0,a1); Vt[j][cq+ 4]=a0; Vt[j][cq+ 5]=a1;
      unpack2(vu0.w,a0,a1); Vt[j][cq+ 6]=a0; Vt[j][cq+ 7]=a1;
      unpack2(vu1.x,a0,a1); Vt[j][cq+ 8]=a0; Vt[j][cq+ 9]=a1;
      unpack2(vu1.y,a0,a1); Vt[j][cq+10]=a0; Vt[j][cq+11]=a1;
      unpack2(vu1.z,a0,a1); Vt[j][cq+12]=a0; Vt[j][cq+13]=a1;
      unpack2(vu1.w,a0,a1); Vt[j][cq+14]=a0; Vt[j][cq+15]=a1;
    }
    __syncthreads();

    // scores: thread (srow, kc) handles keys kc + 16*jj (stride-16 mapping:
    // lane address stride = 68 words, 68%32=4 -> all 32 banks, 2-way = free)
    float s[4] = {0.f,0.f,0.f,0.f};
    #pragma unroll
    for (int d4 = 0; d4 < 16; d4++){
      float4 qv = *(float4*)&Qt[srow][d4*4];
      #pragma unroll
      for (int jj = 0; jj < 4; jj++){
        float4 kv = *(float4*)&Kt[kc + 16*jj][d4*4];
        s[jj] += qv.x*kv.x + qv.y*kv.y + qv.z*kv.z + qv.w*kv.w;
      }
    }
    #pragma unroll
    for (int jj = 0; jj < 4; jj++){
      int mk = mask[b*SS + t0 + kc + 16*jj];
      s[jj] = (mk != 0) ? s[jj] * 0.125f : -1e30f;
    }
    float mloc = fmaxf(fmaxf(s[0],s[1]), fmaxf(s[2],s[3]));
    #pragma unroll
    for (int off=8; off; off>>=1) mloc = fmaxf(mloc, __shfl_xor(mloc, off, 16));
    float m_new = fmaxf(m_run, mloc);
    float alpha = __expf(m_run - m_new);
    float p[4];
    float lloc = 0.f;
    #pragma unroll
    for (int jj = 0; jj < 4; jj++){ p[jj] = __expf(s[jj] - m_new); lloc += p[jj]; }
    #pragma unroll
    for (int off=8; off; off>>=1) lloc += __shfl_xor(lloc, off, 16);
    l_run = l_run * alpha + lloc;
    m_run = m_new;
    #pragma unroll
    for (int jj = 0; jj < 4; jj++) Pt[srow][jj*16 + kc] = p[jj];
    __syncthreads();

    // PV: thread (srow, dc) accumulates o[srow][dc..dc+3]
    o.x *= alpha; o.y *= alpha; o.z *= alpha; o.w *= alpha;
    #pragma unroll
    for (int j4 = 0; j4 < 16; j4++){
      float4 pv = *(float4*)&Pt[srow][j4*4];
      float pa[4] = {pv.x, pv.y, pv.z, pv.w};
      #pragma unroll
      for (int jj = 0; jj < 4; jj++){
        float4 vv = *(float4*)&Vt[j4*4+jj][dc];
        o.x += pa[jj]*vv.x; o.y += pa[jj]*vv.y; o.z += pa[jj]*vv.z; o.w += pa[jj]*vv.w;
      }
    }
    __syncthreads();
  }

  float inv_l = 1.f / l_run;
  ushort4 ou;
  ou.x = f2bf(o.x * inv_l); ou.y = f2bf(o.y * inv_l);
  ou.z = f2bf(o.z * inv_l); ou.w = f2bf(o.w * inv_l);
  u16* dst = ctx + ((size_t)(b*SS + q0 + srow)) * EE + h*DD + dc;
  *(ushort4*)dst = ou;
}

// ---------------- fused residual + LayerNorm (bf16 ctx2 in, bf16 h out) ----------------
__global__ __launch_bounds__(256) void ln_kernel(const u16* __restrict__ c2,
    const float* __restrict__ x, const float* __restrict__ g,
    const float* __restrict__ bta, u16* __restrict__ h){
  int row = blockIdx.x, tid = threadIdx.x;
  uint2 cu = ((const uint2*)(c2 + (size_t)row * EE))[tid];
  float c0,c1,c2f,c3;
  unpack2(cu.x, c0, c1); unpack2(cu.y, c2f, c3);
  float4 xv = ((const float4*)(x + (size_t)row * EE))[tid];
  float4 y = make_float4(c0+xv.x, c1+xv.y, c2f+xv.z, c3+xv.w);
  float s  = y.x + y.y + y.z + y.w;
  float ss = y.x*y.x + y.y*y.y + y.z*y.z + y.w*y.w;
  #pragma unroll
  for (int off=32; off; off>>=1){
    s  += __shfl_xor(s,  off, 64);
    ss += __shfl_xor(ss, off, 64);
  }
  __shared__ float rs[4], rss[4];
  int w = tid >> 6;
  if ((tid & 63) == 0){ rs[w] = s; rss[w] = ss; }
  __syncthreads();
  float tot  = rs[0]+rs[1]+rs[2]+rs[3];
  float tots = rss[0]+rss[1]+rss[2]+rss[3];
  float mu  = tot  * (1.f/EE);
  float var = tots * (1.f/EE) - mu*mu;
  float inv = rsqrtf(var + 1e-5f);
  float4 gv = ((const float4*)g)[tid];
  float4 bv = ((const float4*)bta)[tid];
  ushort4 ou;
  ou.x = f2bf((y.x-mu)*inv*gv.x + bv.x);
  ou.y = f2bf((y.y-mu)*inv*gv.y + bv.y);
  ou.z = f2bf((y.z-mu)*inv*gv.z + bv.z);
  ou.w = f2bf((y.w-mu)*inv*gv.w + bv.w);
  ((ushort4*)(h + (size_t)row * EE))[tid] = ou;
}

// ---------------- t[b,e] = (gsum[b,:]/S) @ W2[:,e] + b2[e]  (f32) ----------------
__global__ __launch_bounds__(256) void w2_kernel(const float* __restrict__ gsum,
    const float* __restrict__ W2, const float* __restrict__ b2, float* __restrict__ t){
  int idx = blockIdx.x * 256 + threadIdx.x;   // 0..4095
  int b = idx >> 10, e = idx & 1023;
  float acc = 0.f;
  #pragma unroll 8
  for (int f=0; f<FF; f++) acc += gsum[b*FF + f] * W2[(size_t)f * EE + e];
  t[idx] = acc * (1.f/SS) + b2[e];
}

// ---------------- out[b,j] = t[b,:] @ Wp[:,j] + bp[j]  (f32) ----------------
__global__ __launch_bounds__(256) void out_kernel(const float* __restrict__ t,
    const float* __restrict__ Wp, const float* __restrict__ bp, float* __restrict__ out){
  int tid = threadIdx.x;
  float part[4][3];
  #pragma unroll
  for (int b=0;b<4;b++) for (int j=0;j<3;j++) part[b][j]=0.f;
  int e0 = tid * 4;
  #pragma unroll
  for (int b=0;b<4;b++){
    float4 tv = *(const float4*)&t[b*EE + e0];
    float ta[4] = {tv.x,tv.y,tv.z,tv.w};
    #pragma unroll
    for (int i=0;i<4;i++){
      int e = e0 + i;
      part[b][0] += ta[i] * Wp[e*3+0];
      part[b][1] += ta[i] * Wp[e*3+1];
      part[b][2] += ta[i] * Wp[e*3+2];
    }
  }
  __shared__ float red[12][4];
  int lane = tid & 63, w = tid >> 6;
  #pragma unroll
  for (int b=0;b<4;b++){
    #pragma unroll
    for (int j=0;j<3;j++){
      float vsum = part[b][j];
      #pragma unroll
      for (int off=32; off; off>>=1) vsum += __shfl_xor(vsum, off, 64);
      if (lane == 0) red[b*3+j][w] = vsum;
    }
  }
  __syncthreads();
  if (tid < 12){
    float ssum = red[tid][0]+red[tid][1]+red[tid][2]+red[tid][3];
    out[tid] = ssum + bp[tid % 3];
  }
}

extern "C" void kernel_launch(void* const* d_in, const int* in_sizes, int n_in,
                              void* d_out, int out_size, void* d_ws, size_t ws_size,
                              hipStream_t stream) {
  const int M = BB * SS;                      // 8192
  const int* ids  = (const int*)d_in[0];
  const int* mask = (const int*)d_in[1];
  const float* emb = (const float*)d_in[2];
  const float* Wq = (const float*)d_in[3];  const float* bq = (const float*)d_in[4];
  const float* Wk = (const float*)d_in[5];  const float* bk = (const float*)d_in[6];
  const float* Wv = (const float*)d_in[7];  const float* bv = (const float*)d_in[8];
  const float* Wo = (const float*)d_in[9];  const float* bo = (const float*)d_in[10];
  const float* lg = (const float*)d_in[11]; const float* lb = (const float*)d_in[12];
  const float* W1 = (const float*)d_in[13]; const float* b1 = (const float*)d_in[14];
  const float* W2 = (const float*)d_in[15]; const float* b2 = (const float*)d_in[16];
  const float* Wp = (const float*)d_in[17]; const float* bp = (const float*)d_in[18];

  // workspace layout (bytes), all offsets 16B-aligned
  char* base = (char*)d_ws;
  const size_t SLOTF = (size_t)M * EE;        // elements per [M,E] matrix
  float* xf   = (float*)base;                          // f32   33.55 MB
  u16*  xbf   = (u16*)(base + SLOTF*4);                // bf16  16.78 MB
  u16*  qbf   = (u16*)(base + SLOTF*6);
  u16*  kbf   = (u16*)(base + SLOTF*8);
  u16*  vbf   = (u16*)(base + SLOTF*10);
  u16*  ctxbf = (u16*)(base + SLOTF*12);
  u16*  c2bf  = qbf;                                   // q dead after attention
  u16*  hbf   = kbf;                                   // k dead after attention
  u16*  WqT   = (u16*)(base + SLOTF*14);               // [E][E] bf16, 2 MB each
  u16*  WkT   = WqT + (size_t)EE*EE;
  u16*  WvT   = WkT + (size_t)EE*EE;
  u16*  WoT   = WvT + (size_t)EE*EE;
  u16*  W1T   = WoT + (size_t)EE*EE;                   // [F][E] bf16, 8 MB
  float* gsum = (float*)(W1T + (size_t)FF*EE);         // [B][F]
  float* tbuf = gsum + BB*FF;                          // [B][E]

  hipMemsetAsync(gsum, 0, BB*FF*sizeof(float), stream);

  embed_kernel<<<M, 256, 0, stream>>>(ids, emb, xf, xbf);

  transpose_bf16<<<dim3(EE/32, EE/32), 256, 0, stream>>>(Wq, WqT, EE, EE);
  transpose_bf16<<<dim3(EE/32, EE/32), 256, 0, stream>>>(Wk, WkT, EE, EE);
  transpose_bf16<<<dim3(EE/32, EE/32), 256, 0, stream>>>(Wv, WvT, EE, EE);
  transpose_bf16<<<dim3(EE/32, EE/32), 256, 0, stream>>>(Wo, WoT, EE, EE);
  transpose_bf16<<<dim3(FF/32, EE/32), 256, 0, stream>>>(W1, W1T, EE, FF);

  dim3 gQ(EE/128, M/128);
  gemm_mfma<0><<<gQ, 256, 0, stream>>>(xbf, WqT, bq, qbf, nullptr, M, EE, EE);
  gemm_mfma<0><<<gQ, 256, 0, stream>>>(xbf, WkT, bk, kbf, nullptr, M, EE, EE);
  gemm_mfma<0><<<gQ, 256, 0, stream>>>(xbf, WvT, bv, vbf, nullptr, M, EE, EE);

  attn_kernel<<<dim3(SS/16, BB*HH), 256, 0, stream>>>(qbf, kbf, vbf, mask, ctxbf);

  gemm_mfma<0><<<gQ, 256, 0, stream>>>(ctxbf, WoT, bo, c2bf, nullptr, M, EE, EE);

  ln_kernel<<<M, 256, 0, stream>>>(c2bf, xf, lg, lb, hbf);

  gemm_mfma<1><<<dim3(FF/128, M/128), 256, 0, stream>>>(hbf, W1T, b1, nullptr, gsum, M, FF, EE);

  w2_kernel<<<16, 256, 0, stream>>>(gsum, W2, b2, tbuf);
  out_kernel<<<1, 256, 0, stream>>>(tbuf, Wp, bp, (float*)d_out);
}

// Round 3
// 770.652 us; speedup vs baseline: 6.4779x; 3.6094x over previous
//
#include <hip/hip_runtime.h>
#include <hip/hip_bf16.h>
#include <math.h>

// Problem constants
#define BB 4
#define SS 2048
#define EE 1024
#define HH 16
#define DD 64
#define FF 4096

typedef unsigned short u16;
typedef unsigned int u32;
typedef __bf16 bf16x8 __attribute__((ext_vector_type(8)));
typedef float f32x4 __attribute__((ext_vector_type(4)));

static __device__ __forceinline__ float gelu_exact(float v){
  return 0.5f * v * (1.0f + erff(v * 0.70710678118654752f));
}

// float -> bf16 (RNE)
static __device__ __forceinline__ u16 f2bf(float f){
  union { float f; u32 u; } x; x.f = f;
  u32 r = x.u + 0x7FFFu + ((x.u >> 16) & 1u);
  return (u16)(r >> 16);
}
// unpack a u32 holding two bf16 (little-endian: elem0 = low half)
static __device__ __forceinline__ void unpack2(u32 u, float& lo, float& hi){
  union { u32 u; float f; } a, b;
  a.u = u << 16; b.u = u & 0xFFFF0000u;
  lo = a.f; hi = b.f;
}

#define GLOAD_LDS16(g, l) \
  __builtin_amdgcn_global_load_lds((const __attribute__((address_space(1))) void*)(g), \
      (__attribute__((address_space(3))) void*)(l), 16, 0, 0)

// ---------------- embedding gather: write f32 (for residual) + bf16 (GEMM A) ----------------
__global__ __launch_bounds__(256) void embed_kernel(const int* __restrict__ ids,
    const float* __restrict__ emb, float* __restrict__ xf, u16* __restrict__ xbf){
  int row = blockIdx.x;
  int id  = ids[row];
  float4 v = ((const float4*)(emb + (size_t)id * EE))[threadIdx.x];
  ((float4*)(xf + (size_t)row * EE))[threadIdx.x] = v;
  ushort4 u; u.x = f2bf(v.x); u.y = f2bf(v.y); u.z = f2bf(v.z); u.w = f2bf(v.w);
  ((ushort4*)(xbf + (size_t)row * EE))[threadIdx.x] = u;
}

// ---------------- weight transpose + f32->bf16: WT[n][k] = W[k][n] ----------------
__global__ __launch_bounds__(256) void transpose_bf16(const float* __restrict__ W,
    u16* __restrict__ WT, int K, int N){
  __shared__ float tile[32][33];
  int n0 = blockIdx.x * 32, k0 = blockIdx.y * 32;
  int tx = threadIdx.x & 31, ty = threadIdx.x >> 5;   // ty 0..7
  #pragma unroll
  for (int i = 0; i < 4; i++)
    tile[ty + 8*i][tx] = W[(size_t)(k0 + ty + 8*i) * N + n0 + tx];
  __syncthreads();
  #pragma unroll
  for (int i = 0; i < 4; i++)
    WT[(size_t)(n0 + ty + 8*i) * K + k0 + tx] = f2bf(tile[tx][ty + 8*i]);
}

// ---------------- bf16 MFMA GEMM: C[M,N] = A[M,K] @ W[K,N] + bias ----------------
// A: bf16 row-major [M,K]. WT: bf16 [N,K] (W transposed). 128x128 tile, BK=32.
// MODE 0: store bf16 C.  MODE 1: gelu + per-batch column-sum atomics into gsum[B][N].
template<int MODE>
__global__ __launch_bounds__(256) void gemm_mfma(const u16* __restrict__ A,
    const u16* __restrict__ WT, const float* __restrict__ bias,
    u16* __restrict__ C, float* __restrict__ gsum, int M, int N, int K){
  __shared__ __attribute__((aligned(16))) u16 As[128 * 32];   // [row][k] 8 KB
  __shared__ __attribute__((aligned(16))) u16 Bs[128 * 32];   // [n][k]   8 KB

  const int tid = threadIdx.x;
  const int l = tid & 63, w = tid >> 6;
  const int lm = l & 15, lq = l >> 4;
  const int wm = (w >> 1) * 64, wn = (w & 1) * 64;
  const int r0 = blockIdx.y * 128, c0 = blockIdx.x * 128;

  const int srow0 = w * 32 + (l >> 2);          // row for instr 0
  const int scol  = (l & 3) * 8;                // k-element offset within row
  const u16* Ab = A  + (size_t)(r0 + srow0) * K + scol;
  const u16* Bb = WT + (size_t)(c0 + srow0) * K + scol;
  u16* AsBase0 = &As[(w * 2)     * 512];
  u16* AsBase1 = &As[(w * 2 + 1) * 512];
  u16* BsBase0 = &Bs[(w * 2)     * 512];
  u16* BsBase1 = &Bs[(w * 2 + 1) * 512];

  f32x4 acc[4][4];
  const f32x4 zero = {0.f, 0.f, 0.f, 0.f};
  #pragma unroll
  for (int mi = 0; mi < 4; mi++)
    #pragma unroll
    for (int ni = 0; ni < 4; ni++) acc[mi][ni] = zero;

  for (int k0 = 0; k0 < K; k0 += 32){
    GLOAD_LDS16(Ab + k0,                    AsBase0);
    GLOAD_LDS16(Ab + (size_t)16 * K + k0,   AsBase1);
    GLOAD_LDS16(Bb + k0,                    BsBase0);
    GLOAD_LDS16(Bb + (size_t)16 * K + k0,   BsBase1);
    __syncthreads();

    bf16x8 af[4], bf[4];
    #pragma unroll
    for (int mi = 0; mi < 4; mi++)
      af[mi] = *(const bf16x8*)&As[(wm + mi*16 + lm) * 32 + lq * 8];
    #pragma unroll
    for (int ni = 0; ni < 4; ni++)
      bf[ni] = *(const bf16x8*)&Bs[(wn + ni*16 + lm) * 32 + lq * 8];
    #pragma unroll
    for (int mi = 0; mi < 4; mi++)
      #pragma unroll
      for (int ni = 0; ni < 4; ni++)
        acc[mi][ni] = __builtin_amdgcn_mfma_f32_16x16x32_bf16(af[mi], bf[ni], acc[mi][ni], 0, 0, 0);
    __syncthreads();
  }

  // C/D layout (verified m89/m91): col = lane&15, row = (lane>>4)*4 + reg
  if constexpr (MODE == 0){
    #pragma unroll
    for (int ni = 0; ni < 4; ni++){
      int col = c0 + wn + ni*16 + lm;
      float bcol = bias[col];
      #pragma unroll
      for (int mi = 0; mi < 4; mi++){
        #pragma unroll
        for (int r = 0; r < 4; r++){
          int row = r0 + wm + mi*16 + lq*4 + r;
          C[(size_t)row * N + col] = f2bf(acc[mi][ni][r] + bcol);
        }
      }
    }
  } else {
    const int batch = r0 >> 11;   // 2048 rows per batch, 128 | 2048
    #pragma unroll
    for (int ni = 0; ni < 4; ni++){
      int col = c0 + wn + ni*16 + lm;
      float bcol = bias[col];
      float cs = 0.f;
      #pragma unroll
      for (int mi = 0; mi < 4; mi++)
        #pragma unroll
        for (int r = 0; r < 4; r++)
          cs += gelu_exact(acc[mi][ni][r] + bcol);
      cs += __shfl_xor(cs, 16, 64);
      cs += __shfl_xor(cs, 32, 64);
      if (lq == 0) atomicAdd(&gsum[(size_t)batch * N + col], cs);
    }
  }
}

// ---------------- MFMA flash attention, bf16 ----------------
// Block: one (b,h), 64 q-rows; 4 waves x 16 q-rows. K-tiles of 64 keys.
// Q stays in registers as A-frags. K staged natural Kt[key][d] (pad 72),
// V staged transposed Vt[d][key] (pad 72). P round-trips through per-wave
// LDS (C-layout -> A-layout, m120 pattern); wave-private, no barrier.
__global__ __launch_bounds__(256) void attn_mfma(const u16* __restrict__ q,
    const u16* __restrict__ k, const u16* __restrict__ v,
    const int* __restrict__ mask, u16* __restrict__ ctx){
  const int bh = blockIdx.y, b = bh >> 4, h = bh & 15;
  const int q0 = blockIdx.x * 64;
  const int tid = threadIdx.x;
  const int w = tid >> 6, l = tid & 63, lm = l & 15, lq = l >> 4;

  __shared__ __attribute__((aligned(16))) u16 Kt[64 * 72];
  __shared__ __attribute__((aligned(16))) u16 Vt[64 * 72];
  __shared__ __attribute__((aligned(16))) u16 Pw[4][16 * 72];
  __shared__ float mb[64];

  // Q A-frags direct from global: A[m=lane&15][k=quad*8+j]
  const u16* qrow = q + (size_t)(b*SS + q0 + w*16 + lm) * EE + h*DD + lq*8;
  const bf16x8 aq0 = *(const bf16x8*)qrow;
  const bf16x8 aq1 = *(const bf16x8*)(qrow + 32);

  f32x4 occ[4];
  const f32x4 zero = {0.f,0.f,0.f,0.f};
  #pragma unroll
  for (int ni = 0; ni < 4; ni++) occ[ni] = zero;
  float m_run[4], l_run[4];
  #pragma unroll
  for (int r = 0; r < 4; r++){ m_run[r] = -1e30f; l_run[r] = 0.f; }

  // staging coords
  const int kkey = tid >> 2, kchunk = tid & 3;          // K: 4 threads/key, 64B contiguous
  const u16* kbase = k + (size_t)(b*SS + kkey) * EE + h*DD + kchunk*16;
  const int vkey = tid & 63, vd0 = (tid >> 6) * 16;     // V: wave covers all 64 keys
  const u16* vbase = v + (size_t)(b*SS + vkey) * EE + h*DD + vd0;

  for (int t0 = 0; t0 < SS; t0 += 64){
    // stage K natural layout
    uint4 kv0 = *(const uint4*)(kbase + (size_t)t0 * EE);
    uint4 kv1 = *(const uint4*)(kbase + (size_t)t0 * EE + 8);
    *(uint4*)&Kt[kkey*72 + kchunk*16]     = kv0;
    *(uint4*)&Kt[kkey*72 + kchunk*16 + 8] = kv1;
    // stage V transposed (b16 scatter: all 32 banks, 2-way same-word = free)
    union { uint4 u; u16 s[8]; } va, vb;
    va.u = *(const uint4*)(vbase + (size_t)t0 * EE);
    vb.u = *(const uint4*)(vbase + (size_t)t0 * EE + 8);
    #pragma unroll
    for (int i = 0; i < 8; i++){
      Vt[(vd0 + i)    *72 + vkey] = va.s[i];
      Vt[(vd0 + 8 + i)*72 + vkey] = vb.s[i];
    }
    if (tid < 64) mb[tid] = (mask[b*SS + t0 + tid] != 0) ? 0.f : -1e30f;
    __syncthreads();

    // QK^T: 8 MFMA -> sc[ni], C-layout col=key(lane&15 within 16-tile), row=lq*4+r
    f32x4 sc[4];
    #pragma unroll
    for (int ni = 0; ni < 4; ni++){
      bf16x8 b0 = *(const bf16x8*)&Kt[(ni*16 + lm)*72 + lq*8];
      bf16x8 b1 = *(const bf16x8*)&Kt[(ni*16 + lm)*72 + 32 + lq*8];
      sc[ni] = zero;
      sc[ni] = __builtin_amdgcn_mfma_f32_16x16x32_bf16(aq0, b0, sc[ni], 0, 0, 0);
      sc[ni] = __builtin_amdgcn_mfma_f32_16x16x32_bf16(aq1, b1, sc[ni], 0, 0, 0);
    }

    // scale + mask
    float sv[4][4];
    #pragma unroll
    for (int ni = 0; ni < 4; ni++){
      float mbias = mb[ni*16 + lm];
      #pragma unroll
      for (int r = 0; r < 4; r++) sv[ni][r] = sc[ni][r] * 0.125f + mbias;
    }

    // online softmax per q-row (stats replicated across the 16-lane col group)
    float alpha[4];
    #pragma unroll
    for (int r = 0; r < 4; r++){
      float mm = fmaxf(fmaxf(sv[0][r], sv[1][r]), fmaxf(sv[2][r], sv[3][r]));
      #pragma unroll
      for (int off = 8; off; off >>= 1) mm = fmaxf(mm, __shfl_xor(mm, off, 64));
      float mn = fmaxf(m_run[r], mm);
      alpha[r] = __expf(m_run[r] - mn);
      m_run[r] = mn;
      float ls = 0.f;
      #pragma unroll
      for (int ni = 0; ni < 4; ni++){ sv[ni][r] = __expf(sv[ni][r] - mn); ls += sv[ni][r]; }
      #pragma unroll
      for (int off = 8; off; off >>= 1) ls += __shfl_xor(ls, off, 64);
      l_run[r] = l_run[r] * alpha[r] + ls;
    }

    // P: C-layout -> LDS (bf16) -> A-layout frags (wave-private, no barrier)
    #pragma unroll
    for (int ni = 0; ni < 4; ni++)
      #pragma unroll
      for (int r = 0; r < 4; r++)
        Pw[w][(lq*4 + r)*72 + ni*16 + lm] = f2bf(sv[ni][r]);
    bf16x8 ap0 = *(const bf16x8*)&Pw[w][lm*72 + lq*8];
    bf16x8 ap1 = *(const bf16x8*)&Pw[w][lm*72 + 32 + lq*8];

    // PV: rescale + 8 MFMA. B[k=key][n=d] from Vt[d][key]
    #pragma unroll
    for (int ni = 0; ni < 4; ni++){
      #pragma unroll
      for (int r = 0; r < 4; r++) occ[ni][r] *= alpha[r];
      bf16x8 b0 = *(const bf16x8*)&Vt[(ni*16 + lm)*72 + lq*8];
      bf16x8 b1 = *(const bf16x8*)&Vt[(ni*16 + lm)*72 + 32 + lq*8];
      occ[ni] = __builtin_amdgcn_mfma_f32_16x16x32_bf16(ap0, b0, occ[ni], 0, 0, 0);
      occ[ni] = __builtin_amdgcn_mfma_f32_16x16x32_bf16(ap1, b1, occ[ni], 0, 0, 0);
    }
    __syncthreads();
  }

  float inv[4];
  #pragma unroll
  for (int r = 0; r < 4; r++) inv[r] = 1.f / l_run[r];
  #pragma unroll
  for (int ni = 0; ni < 4; ni++){
    int col = h*DD + ni*16 + lm;
    #pragma unroll
    for (int r = 0; r < 4; r++){
      int row = q0 + w*16 + lq*4 + r;
      ctx[(size_t)(b*SS + row) * EE + col] = f2bf(occ[ni][r] * inv[r]);
    }
  }
}

// ---------------- fused residual + LayerNorm (bf16 ctx2 in, bf16 h out) ----------------
__global__ __launch_bounds__(256) void ln_kernel(const u16* __restrict__ c2,
    const float* __restrict__ x, const float* __restrict__ g,
    const float* __restrict__ bta, u16* __restrict__ h){
  int row = blockIdx.x, tid = threadIdx.x;
  uint2 cu = ((const uint2*)(c2 + (size_t)row * EE))[tid];
  float c0,c1,c2f,c3;
  unpack2(cu.x, c0, c1); unpack2(cu.y, c2f, c3);
  float4 xv = ((const float4*)(x + (size_t)row * EE))[tid];
  float4 y = make_float4(c0+xv.x, c1+xv.y, c2f+xv.z, c3+xv.w);
  float s  = y.x + y.y + y.z + y.w;
  float ss = y.x*y.x + y.y*y.y + y.z*y.z + y.w*y.w;
  #pragma unroll
  for (int off=32; off; off>>=1){
    s  += __shfl_xor(s,  off, 64);
    ss += __shfl_xor(ss, off, 64);
  }
  __shared__ float rs[4], rss[4];
  int w = tid >> 6;
  if ((tid & 63) == 0){ rs[w] = s; rss[w] = ss; }
  __syncthreads();
  float tot  = rs[0]+rs[1]+rs[2]+rs[3];
  float tots = rss[0]+rss[1]+rss[2]+rss[3];
  float mu  = tot  * (1.f/EE);
  float var = tots * (1.f/EE) - mu*mu;
  float inv = rsqrtf(var + 1e-5f);
  float4 gv = ((const float4*)g)[tid];
  float4 bv = ((const float4*)bta)[tid];
  ushort4 ou;
  ou.x = f2bf((y.x-mu)*inv*gv.x + bv.x);
  ou.y = f2bf((y.y-mu)*inv*gv.y + bv.y);
  ou.z = f2bf((y.z-mu)*inv*gv.z + bv.z);
  ou.w = f2bf((y.w-mu)*inv*gv.w + bv.w);
  ((ushort4*)(h + (size_t)row * EE))[tid] = ou;
}

// ---------------- W2Wp[f][j] = sum_e W2[f][e] * Wp[e][j] ----------------
__global__ __launch_bounds__(256) void w2wp_kernel(const float* __restrict__ W2,
    const float* __restrict__ Wp, float* __restrict__ W2Wp){
  int f0 = blockIdx.x * 8;
  int tid = threadIdx.x;
  int e0 = tid * 4;
  float wp[4][3];
  #pragma unroll
  for (int t = 0; t < 4; t++)
    #pragma unroll
    for (int j = 0; j < 3; j++) wp[t][j] = Wp[(e0 + t)*3 + j];
  __shared__ float red[3][4];
  for (int i = 0; i < 8; i++){
    int f = f0 + i;
    float4 wv = ((const float4*)(W2 + (size_t)f * EE))[tid];
    float w4[4] = {wv.x, wv.y, wv.z, wv.w};
    float p[3] = {0.f, 0.f, 0.f};
    #pragma unroll
    for (int t = 0; t < 4; t++)
      #pragma unroll
      for (int j = 0; j < 3; j++) p[j] += w4[t] * wp[t][j];
    #pragma unroll
    for (int j = 0; j < 3; j++){
      float sj = p[j];
      #pragma unroll
      for (int off = 32; off; off >>= 1) sj += __shfl_xor(sj, off, 64);
      if ((tid & 63) == 0) red[j][tid >> 6] = sj;
    }
    __syncthreads();
    if (tid < 3) W2Wp[f*3 + tid] = red[tid][0] + red[tid][1] + red[tid][2] + red[tid][3];
    __syncthreads();
  }
}

// ---------------- out[b,j] = sum_f (gsum[b,f]/S) W2Wp[f,j] + (b2@Wp)[j] + bp[j] ----------------
__global__ __launch_bounds__(256) void out_final(const float* __restrict__ gsum,
    const float* __restrict__ W2Wp, const float* __restrict__ b2,
    const float* __restrict__ Wp, const float* __restrict__ bp, float* __restrict__ out){
  int tid = threadIdx.x;
  float part[4][3];
  #pragma unroll
  for (int b = 0; b < 4; b++)
    #pragma unroll
    for (int j = 0; j < 3; j++) part[b][j] = 0.f;
  for (int f = tid; f < FF; f += 256){
    float w0 = W2Wp[f*3], w1 = W2Wp[f*3+1], w2v = W2Wp[f*3+2];
    #pragma unroll
    for (int b = 0; b < 4; b++){
      float g = gsum[b*FF + f] * (1.f/SS);
      part[b][0] += g * w0; part[b][1] += g * w1; part[b][2] += g * w2v;
    }
  }
  float bb[3] = {0.f, 0.f, 0.f};
  for (int e = tid; e < EE; e += 256){
    float bv = b2[e];
    bb[0] += bv * Wp[e*3]; bb[1] += bv * Wp[e*3+1]; bb[2] += bv * Wp[e*3+2];
  }
  __shared__ float red[15][4];
  int lane = tid & 63, w = tid >> 6;
  #pragma unroll
  for (int b = 0; b < 4; b++)
    #pragma unroll
    for (int j = 0; j < 3; j++){
      float s = part[b][j];
      #pragma unroll
      for (int off = 32; off; off >>= 1) s += __shfl_xor(s, off, 64);
      if (lane == 0) red[b*3 + j][w] = s;
    }
  #pragma unroll
  for (int j = 0; j < 3; j++){
    float s = bb[j];
    #pragma unroll
    for (int off = 32; off; off >>= 1) s += __shfl_xor(s, off, 64);
    if (lane == 0) red[12 + j][w] = s;
  }
  __syncthreads();
  if (tid < 12){
    int j = tid % 3;
    float s  = red[tid][0] + red[tid][1] + red[tid][2] + red[tid][3];
    float bj = red[12+j][0] + red[12+j][1] + red[12+j][2] + red[12+j][3];
    out[tid] = s + bj + bp[j];
  }
}

extern "C" void kernel_launch(void* const* d_in, const int* in_sizes, int n_in,
                              void* d_out, int out_size, void* d_ws, size_t ws_size,
                              hipStream_t stream) {
  const int M = BB * SS;                      // 8192
  const int* ids  = (const int*)d_in[0];
  const int* mask = (const int*)d_in[1];
  const float* emb = (const float*)d_in[2];
  const float* Wq = (const float*)d_in[3];  const float* bq = (const float*)d_in[4];
  const float* Wk = (const float*)d_in[5];  const float* bk = (const float*)d_in[6];
  const float* Wv = (const float*)d_in[7];  const float* bv = (const float*)d_in[8];
  const float* Wo = (const float*)d_in[9];  const float* bo = (const float*)d_in[10];
  const float* lg = (const float*)d_in[11]; const float* lb = (const float*)d_in[12];
  const float* W1 = (const float*)d_in[13]; const float* b1 = (const float*)d_in[14];
  const float* W2 = (const float*)d_in[15]; const float* b2 = (const float*)d_in[16];
  const float* Wp = (const float*)d_in[17]; const float* bp = (const float*)d_in[18];

  // workspace layout (bytes), all offsets 16B-aligned
  char* base = (char*)d_ws;
  const size_t SLOTF = (size_t)M * EE;        // elements per [M,E] matrix
  float* xf   = (float*)base;                          // f32   33.55 MB
  u16*  xbf   = (u16*)(base + SLOTF*4);                // bf16  16.78 MB
  u16*  qbf   = (u16*)(base + SLOTF*6);
  u16*  kbf   = (u16*)(base + SLOTF*8);
  u16*  vbf   = (u16*)(base + SLOTF*10);
  u16*  ctxbf = (u16*)(base + SLOTF*12);
  u16*  c2bf  = qbf;                                   // q dead after attention
  u16*  hbf   = kbf;                                   // k dead after attention
  u16*  WqT   = (u16*)(base + SLOTF*14);               // [E][E] bf16, 2 MB each
  u16*  WkT   = WqT + (size_t)EE*EE;
  u16*  WvT   = WkT + (size_t)EE*EE;
  u16*  WoT   = WvT + (size_t)EE*EE;
  u16*  W1T   = WoT + (size_t)EE*EE;                   // [F][E] bf16, 8 MB
  float* gsum = (float*)(W1T + (size_t)FF*EE);         // [B][F]
  float* w2wp = gsum + BB*FF;                          // [F][3]

  hipMemsetAsync(gsum, 0, BB*FF*sizeof(float), stream);

  embed_kernel<<<M, 256, 0, stream>>>(ids, emb, xf, xbf);

  transpose_bf16<<<dim3(EE/32, EE/32), 256, 0, stream>>>(Wq, WqT, EE, EE);
  transpose_bf16<<<dim3(EE/32, EE/32), 256, 0, stream>>>(Wk, WkT, EE, EE);
  transpose_bf16<<<dim3(EE/32, EE/32), 256, 0, stream>>>(Wv, WvT, EE, EE);
  transpose_bf16<<<dim3(EE/32, EE/32), 256, 0, stream>>>(Wo, WoT, EE, EE);
  transpose_bf16<<<dim3(FF/32, EE/32), 256, 0, stream>>>(W1, W1T, EE, FF);
  w2wp_kernel<<<FF/8, 256, 0, stream>>>(W2, Wp, w2wp);

  dim3 gQ(EE/128, M/128);
  gemm_mfma<0><<<gQ, 256, 0, stream>>>(xbf, WqT, bq, qbf, nullptr, M, EE, EE);
  gemm_mfma<0><<<gQ, 256, 0, stream>>>(xbf, WkT, bk, kbf, nullptr, M, EE, EE);
  gemm_mfma<0><<<gQ, 256, 0, stream>>>(xbf, WvT, bv, vbf, nullptr, M, EE, EE);

  attn_mfma<<<dim3(SS/64, BB*HH), 256, 0, stream>>>(qbf, kbf, vbf, mask, ctxbf);

  gemm_mfma<0><<<gQ, 256, 0, stream>>>(ctxbf, WoT, bo, c2bf, nullptr, M, EE, EE);

  ln_kernel<<<M, 256, 0, stream>>>(c2bf, xf, lg, lb, hbf);

  gemm_mfma<1><<<dim3(FF/128, M/128), 256, 0, stream>>>(hbf, W1T, b1, nullptr, gsum, M, FF, EE);

  out_final<<<1, 256, 0, stream>>>(gsum, w2wp, b2, Wp, bp, (float*)d_out);
}

// Round 4
// 646.544 us; speedup vs baseline: 7.7213x; 1.1920x over previous
//
#include <hip/hip_runtime.h>
#include <hip/hip_bf16.h>
#include <math.h>

// Problem constants
#define BB 4
#define SS 2048
#define EE 1024
#define HH 16
#define DD 64
#define FF 4096

typedef unsigned short u16;
typedef unsigned int u32;
typedef __bf16 bf16x8 __attribute__((ext_vector_type(8)));
typedef float f32x4 __attribute__((ext_vector_type(4)));

static __device__ __forceinline__ float gelu_exact(float v){
  return 0.5f * v * (1.0f + erff(v * 0.70710678118654752f));
}

// float -> bf16 (RNE)
static __device__ __forceinline__ u16 f2bf(float f){
  union { float f; u32 u; } x; x.f = f;
  u32 r = x.u + 0x7FFFu + ((x.u >> 16) & 1u);
  return (u16)(r >> 16);
}
// unpack a u32 holding two bf16 (little-endian: elem0 = low half)
static __device__ __forceinline__ void unpack2(u32 u, float& lo, float& hi){
  union { u32 u; float f; } a, b;
  a.u = u << 16; b.u = u & 0xFFFF0000u;
  lo = a.f; hi = b.f;
}

#define GLOAD_LDS16(g, l) \
  __builtin_amdgcn_global_load_lds((const __attribute__((address_space(1))) void*)(g), \
      (__attribute__((address_space(3))) void*)(l), 16, 0, 0)

// ---------------- embedding gather: write f32 (for residual) + bf16 (GEMM A) ----------------
__global__ __launch_bounds__(256) void embed_kernel(const int* __restrict__ ids,
    const float* __restrict__ emb, float* __restrict__ xf, u16* __restrict__ xbf){
  int row = blockIdx.x;
  int id  = ids[row];
  float4 v = ((const float4*)(emb + (size_t)id * EE))[threadIdx.x];
  ((float4*)(xf + (size_t)row * EE))[threadIdx.x] = v;
  ushort4 u; u.x = f2bf(v.x); u.y = f2bf(v.y); u.z = f2bf(v.z); u.w = f2bf(v.w);
  ((ushort4*)(xbf + (size_t)row * EE))[threadIdx.x] = u;
}

// ---------------- weight transpose + f32->bf16: WT[n][k] = W[k][n] ----------------
__global__ __launch_bounds__(256) void transpose_bf16(const float* __restrict__ W,
    u16* __restrict__ WT, int K, int N){
  __shared__ float tile[32][33];
  int n0 = blockIdx.x * 32, k0 = blockIdx.y * 32;
  int tx = threadIdx.x & 31, ty = threadIdx.x >> 5;   // ty 0..7
  #pragma unroll
  for (int i = 0; i < 4; i++)
    tile[ty + 8*i][tx] = W[(size_t)(k0 + ty + 8*i) * N + n0 + tx];
  __syncthreads();
  #pragma unroll
  for (int i = 0; i < 4; i++)
    WT[(size_t)(n0 + ty + 8*i) * K + k0 + tx] = f2bf(tile[tx][ty + 8*i]);
}

// ---------------- bf16 MFMA GEMM: C[M,N] = A[M,K] @ W[K,N] + bias ----------------
// A: bf16 row-major [M,K]. WT: bf16 [N,K] (W transposed). 128x128 tile, BK=32.
// MODE 0: store bf16 C.
// MODE 1: gelu + per-batch column-sum atomics into gsum[B][N].
// MODE 2: fused QKV: WT spans 3*N rows; output slab sel = col>>10 into C + sel*M*N,
//         bias selected from {bias, biasB, biasC}.
template<int MODE>
__global__ __launch_bounds__(256) void gemm_mfma(const u16* __restrict__ A,
    const u16* __restrict__ WT, const float* __restrict__ bias,
    const float* __restrict__ biasB, const float* __restrict__ biasC,
    u16* __restrict__ C, float* __restrict__ gsum, int M, int N, int K){
  __shared__ __attribute__((aligned(16))) u16 As[128 * 32];   // [row][k] 8 KB
  __shared__ __attribute__((aligned(16))) u16 Bs[128 * 32];   // [n][k]   8 KB

  const int tid = threadIdx.x;
  const int l = tid & 63, w = tid >> 6;
  const int lm = l & 15, lq = l >> 4;
  const int wm = (w >> 1) * 64, wn = (w & 1) * 64;
  const int r0 = blockIdx.y * 128, c0 = blockIdx.x * 128;

  const int srow0 = w * 32 + (l >> 2);          // row for instr 0
  const int scol  = (l & 3) * 8;                // k-element offset within row
  const u16* Ab = A  + (size_t)(r0 + srow0) * K + scol;
  const u16* Bb = WT + (size_t)(c0 + srow0) * K + scol;
  u16* AsBase0 = &As[(w * 2)     * 512];
  u16* AsBase1 = &As[(w * 2 + 1) * 512];
  u16* BsBase0 = &Bs[(w * 2)     * 512];
  u16* BsBase1 = &Bs[(w * 2 + 1) * 512];

  f32x4 acc[4][4];
  const f32x4 zero = {0.f, 0.f, 0.f, 0.f};
  #pragma unroll
  for (int mi = 0; mi < 4; mi++)
    #pragma unroll
    for (int ni = 0; ni < 4; ni++) acc[mi][ni] = zero;

  for (int k0 = 0; k0 < K; k0 += 32){
    GLOAD_LDS16(Ab + k0,                    AsBase0);
    GLOAD_LDS16(Ab + (size_t)16 * K + k0,   AsBase1);
    GLOAD_LDS16(Bb + k0,                    BsBase0);
    GLOAD_LDS16(Bb + (size_t)16 * K + k0,   BsBase1);
    __syncthreads();

    bf16x8 af[4], bf[4];
    #pragma unroll
    for (int mi = 0; mi < 4; mi++)
      af[mi] = *(const bf16x8*)&As[(wm + mi*16 + lm) * 32 + lq * 8];
    #pragma unroll
    for (int ni = 0; ni < 4; ni++)
      bf[ni] = *(const bf16x8*)&Bs[(wn + ni*16 + lm) * 32 + lq * 8];
    #pragma unroll
    for (int mi = 0; mi < 4; mi++)
      #pragma unroll
      for (int ni = 0; ni < 4; ni++)
        acc[mi][ni] = __builtin_amdgcn_mfma_f32_16x16x32_bf16(af[mi], bf[ni], acc[mi][ni], 0, 0, 0);
    __syncthreads();
  }

  // C/D layout (verified m89/m91): col = lane&15, row = (lane>>4)*4 + reg
  if constexpr (MODE == 0){
    #pragma unroll
    for (int ni = 0; ni < 4; ni++){
      int col = c0 + wn + ni*16 + lm;
      float bcol = bias[col];
      #pragma unroll
      for (int mi = 0; mi < 4; mi++){
        #pragma unroll
        for (int r = 0; r < 4; r++){
          int row = r0 + wm + mi*16 + lq*4 + r;
          C[(size_t)row * N + col] = f2bf(acc[mi][ni][r] + bcol);
        }
      }
    }
  } else if constexpr (MODE == 2){
    #pragma unroll
    for (int ni = 0; ni < 4; ni++){
      int col3 = c0 + wn + ni*16 + lm;      // 0..3071, never crosses a 1024 boundary within 16
      int sel  = col3 >> 10;
      int colm = col3 & 1023;
      const float* bp_ = (sel == 0) ? bias : ((sel == 1) ? biasB : biasC);
      float bcol = bp_[colm];
      u16* dst = C + (size_t)sel * ((size_t)M * N);
      #pragma unroll
      for (int mi = 0; mi < 4; mi++){
        #pragma unroll
        for (int r = 0; r < 4; r++){
          int row = r0 + wm + mi*16 + lq*4 + r;
          dst[(size_t)row * N + colm] = f2bf(acc[mi][ni][r] + bcol);
        }
      }
    }
  } else {
    const int batch = r0 >> 11;   // 2048 rows per batch, 128 | 2048
    #pragma unroll
    for (int ni = 0; ni < 4; ni++){
      int col = c0 + wn + ni*16 + lm;
      float bcol = bias[col];
      float cs = 0.f;
      #pragma unroll
      for (int mi = 0; mi < 4; mi++)
        #pragma unroll
        for (int r = 0; r < 4; r++)
          cs += gelu_exact(acc[mi][ni][r] + bcol);
      cs += __shfl_xor(cs, 16, 64);
      cs += __shfl_xor(cs, 32, 64);
      if (lq == 0) atomicAdd(&gsum[(size_t)batch * N + col], cs);
    }
  }
}

// ---------------- MFMA flash attention, bf16, no-max softmax ----------------
// Block: one (b,h), 128 q-rows; 8 waves x 16 q-rows; 512 threads. K-tiles of 64.
// Scores here are O(1e-3): exp without max-subtraction is overflow-safe (clamped
// at 60 as a guard; masked -> -1e30 -> exp -> 0). l accumulates as per-lane
// partials, reduced once after the K-loop -> zero per-tile shuffles/rescales.
// Threads 0-255 stage K (natural [key][d], pad 72); threads 256-511 stage V
// transposed ([d][key], pad 72, b16 scatter 2-way = free).
__global__ __launch_bounds__(512) void attn_mfma(const u16* __restrict__ q,
    const u16* __restrict__ k, const u16* __restrict__ v,
    const int* __restrict__ mask, u16* __restrict__ ctx){
  const int bh = blockIdx.y, b = bh >> 4, h = bh & 15;
  const int q0 = blockIdx.x * 128;
  const int tid = threadIdx.x;
  const int w = tid >> 6, l = tid & 63, lm = l & 15, lq = l >> 4;

  __shared__ __attribute__((aligned(16))) u16 Kt[64 * 72];
  __shared__ __attribute__((aligned(16))) u16 Vt[64 * 72];
  __shared__ __attribute__((aligned(16))) u16 Pw[8][16 * 72];
  __shared__ float mb[64];

  // Q A-frags direct from global: A[m=lane&15][k=quad*8+j]
  const u16* qrow = q + (size_t)(b*SS + q0 + w*16 + lm) * EE + h*DD + lq*8;
  const bf16x8 aq0 = *(const bf16x8*)qrow;
  const bf16x8 aq1 = *(const bf16x8*)(qrow + 32);

  f32x4 occ[4];
  const f32x4 zero = {0.f,0.f,0.f,0.f};
  #pragma unroll
  for (int ni = 0; ni < 4; ni++) occ[ni] = zero;
  float l_part[4] = {0.f, 0.f, 0.f, 0.f};

  // staging coords
  const int kkey = (tid & 255) >> 2, kchunk = tid & 3;   // K: 4 threads/key
  const u16* kbase = k + (size_t)(b*SS + kkey) * EE + h*DD + kchunk*16;
  const int vkey = tid & 63, vd0 = ((tid >> 6) & 3) * 16; // V: wave covers 64 keys
  const u16* vbase = v + (size_t)(b*SS + vkey) * EE + h*DD + vd0;

  for (int t0 = 0; t0 < SS; t0 += 64){
    if (tid < 256){
      uint4 kv0 = *(const uint4*)(kbase + (size_t)t0 * EE);
      uint4 kv1 = *(const uint4*)(kbase + (size_t)t0 * EE + 8);
      *(uint4*)&Kt[kkey*72 + kchunk*16]     = kv0;
      *(uint4*)&Kt[kkey*72 + kchunk*16 + 8] = kv1;
      if (tid < 64) mb[tid] = (mask[b*SS + t0 + tid] != 0) ? 0.f : -1e30f;
    } else {
      union { uint4 u; u16 s[8]; } va, vb;
      va.u = *(const uint4*)(vbase + (size_t)t0 * EE);
      vb.u = *(const uint4*)(vbase + (size_t)t0 * EE + 8);
      #pragma unroll
      for (int i = 0; i < 8; i++){
        Vt[(vd0 + i)    *72 + vkey] = va.s[i];
        Vt[(vd0 + 8 + i)*72 + vkey] = vb.s[i];
      }
    }
    __syncthreads();

    // QK^T: 8 MFMA; C-layout col=key-within-16 (lm), row=lq*4+r
    f32x4 sc[4];
    #pragma unroll
    for (int ni = 0; ni < 4; ni++){
      bf16x8 b0 = *(const bf16x8*)&Kt[(ni*16 + lm)*72 + lq*8];
      bf16x8 b1 = *(const bf16x8*)&Kt[(ni*16 + lm)*72 + 32 + lq*8];
      sc[ni] = zero;
      sc[ni] = __builtin_amdgcn_mfma_f32_16x16x32_bf16(aq0, b0, sc[ni], 0, 0, 0);
      sc[ni] = __builtin_amdgcn_mfma_f32_16x16x32_bf16(aq1, b1, sc[ni], 0, 0, 0);
    }

    // p = exp(s/8 + maskbias); accumulate l per-lane; P -> wave-private LDS
    #pragma unroll
    for (int ni = 0; ni < 4; ni++){
      float mbias = mb[ni*16 + lm];
      #pragma unroll
      for (int r = 0; r < 4; r++){
        float s = fminf(fmaf(sc[ni][r], 0.125f, mbias), 60.f);
        float p = __expf(s);
        l_part[r] += p;
        Pw[w][(lq*4 + r)*72 + ni*16 + lm] = f2bf(p);
      }
    }
    bf16x8 ap0 = *(const bf16x8*)&Pw[w][lm*72 + lq*8];
    bf16x8 ap1 = *(const bf16x8*)&Pw[w][lm*72 + 32 + lq*8];

    // PV: 8 MFMA, no rescale
    #pragma unroll
    for (int ni = 0; ni < 4; ni++){
      bf16x8 b0 = *(const bf16x8*)&Vt[(ni*16 + lm)*72 + lq*8];
      bf16x8 b1 = *(const bf16x8*)&Vt[(ni*16 + lm)*72 + 32 + lq*8];
      occ[ni] = __builtin_amdgcn_mfma_f32_16x16x32_bf16(ap0, b0, occ[ni], 0, 0, 0);
      occ[ni] = __builtin_amdgcn_mfma_f32_16x16x32_bf16(ap1, b1, occ[ni], 0, 0, 0);
    }
    __syncthreads();
  }

  // final l reduction across the 16-lane column group (lm bits), once
  float inv[4];
  #pragma unroll
  for (int r = 0; r < 4; r++){
    float s = l_part[r];
    s += __shfl_xor(s, 1, 64);
    s += __shfl_xor(s, 2, 64);
    s += __shfl_xor(s, 4, 64);
    s += __shfl_xor(s, 8, 64);
    inv[r] = 1.f / s;
  }
  #pragma unroll
  for (int ni = 0; ni < 4; ni++){
    int col = h*DD + ni*16 + lm;
    #pragma unroll
    for (int r = 0; r < 4; r++){
      int row = q0 + w*16 + lq*4 + r;
      ctx[(size_t)(b*SS + row) * EE + col] = f2bf(occ[ni][r] * inv[r]);
    }
  }
}

// ---------------- fused residual + LayerNorm (bf16 ctx2 in, bf16 h out) ----------------
__global__ __launch_bounds__(256) void ln_kernel(const u16* __restrict__ c2,
    const float* __restrict__ x, const float* __restrict__ g,
    const float* __restrict__ bta, u16* __restrict__ h){
  int row = blockIdx.x, tid = threadIdx.x;
  uint2 cu = ((const uint2*)(c2 + (size_t)row * EE))[tid];
  float c0,c1,c2f,c3;
  unpack2(cu.x, c0, c1); unpack2(cu.y, c2f, c3);
  float4 xv = ((const float4*)(x + (size_t)row * EE))[tid];
  float4 y = make_float4(c0+xv.x, c1+xv.y, c2f+xv.z, c3+xv.w);
  float s  = y.x + y.y + y.z + y.w;
  float ss = y.x*y.x + y.y*y.y + y.z*y.z + y.w*y.w;
  #pragma unroll
  for (int off=32; off; off>>=1){
    s  += __shfl_xor(s,  off, 64);
    ss += __shfl_xor(ss, off, 64);
  }
  __shared__ float rs[4], rss[4];
  int w = tid >> 6;
  if ((tid & 63) == 0){ rs[w] = s; rss[w] = ss; }
  __syncthreads();
  float tot  = rs[0]+rs[1]+rs[2]+rs[3];
  float tots = rss[0]+rss[1]+rss[2]+rss[3];
  float mu  = tot  * (1.f/EE);
  float var = tots * (1.f/EE) - mu*mu;
  float inv = rsqrtf(var + 1e-5f);
  float4 gv = ((const float4*)g)[tid];
  float4 bv = ((const float4*)bta)[tid];
  ushort4 ou;
  ou.x = f2bf((y.x-mu)*inv*gv.x + bv.x);
  ou.y = f2bf((y.y-mu)*inv*gv.y + bv.y);
  ou.z = f2bf((y.z-mu)*inv*gv.z + bv.z);
  ou.w = f2bf((y.w-mu)*inv*gv.w + bv.w);
  ((ushort4*)(h + (size_t)row * EE))[tid] = ou;
}

// ---------------- W2Wp[f][j] = sum_e W2[f][e] * Wp[e][j] ----------------
__global__ __launch_bounds__(256) void w2wp_kernel(const float* __restrict__ W2,
    const float* __restrict__ Wp, float* __restrict__ W2Wp){
  int f0 = blockIdx.x * 8;
  int tid = threadIdx.x;
  int e0 = tid * 4;
  float wp[4][3];
  #pragma unroll
  for (int t = 0; t < 4; t++)
    #pragma unroll
    for (int j = 0; j < 3; j++) wp[t][j] = Wp[(e0 + t)*3 + j];
  __shared__ float red[3][4];
  for (int i = 0; i < 8; i++){
    int f = f0 + i;
    float4 wv = ((const float4*)(W2 + (size_t)f * EE))[tid];
    float w4[4] = {wv.x, wv.y, wv.z, wv.w};
    float p[3] = {0.f, 0.f, 0.f};
    #pragma unroll
    for (int t = 0; t < 4; t++)
      #pragma unroll
      for (int j = 0; j < 3; j++) p[j] += w4[t] * wp[t][j];
    #pragma unroll
    for (int j = 0; j < 3; j++){
      float sj = p[j];
      #pragma unroll
      for (int off = 32; off; off >>= 1) sj += __shfl_xor(sj, off, 64);
      if ((tid & 63) == 0) red[j][tid >> 6] = sj;
    }
    __syncthreads();
    if (tid < 3) W2Wp[f*3 + tid] = red[tid][0] + red[tid][1] + red[tid][2] + red[tid][3];
    __syncthreads();
  }
}

// ---------------- out[b,j] = sum_f (gsum[b,f]/S) W2Wp[f,j] + (b2@Wp)[j] + bp[j] ----------------
__global__ __launch_bounds__(256) void out_final(const float* __restrict__ gsum,
    const float* __restrict__ W2Wp, const float* __restrict__ b2,
    const float* __restrict__ Wp, const float* __restrict__ bp, float* __restrict__ out){
  int tid = threadIdx.x;
  float part[4][3];
  #pragma unroll
  for (int b = 0; b < 4; b++)
    #pragma unroll
    for (int j = 0; j < 3; j++) part[b][j] = 0.f;
  for (int f = tid; f < FF; f += 256){
    float w0 = W2Wp[f*3], w1 = W2Wp[f*3+1], w2v = W2Wp[f*3+2];
    #pragma unroll
    for (int b = 0; b < 4; b++){
      float g = gsum[b*FF + f] * (1.f/SS);
      part[b][0] += g * w0; part[b][1] += g * w1; part[b][2] += g * w2v;
    }
  }
  float bb[3] = {0.f, 0.f, 0.f};
  for (int e = tid; e < EE; e += 256){
    float bv = b2[e];
    bb[0] += bv * Wp[e*3]; bb[1] += bv * Wp[e*3+1]; bb[2] += bv * Wp[e*3+2];
  }
  __shared__ float red[15][4];
  int lane = tid & 63, w = tid >> 6;
  #pragma unroll
  for (int b = 0; b < 4; b++)
    #pragma unroll
    for (int j = 0; j < 3; j++){
      float s = part[b][j];
      #pragma unroll
      for (int off = 32; off; off >>= 1) s += __shfl_xor(s, off, 64);
      if (lane == 0) red[b*3 + j][w] = s;
    }
  #pragma unroll
  for (int j = 0; j < 3; j++){
    float s = bb[j];
    #pragma unroll
    for (int off = 32; off; off >>= 1) s += __shfl_xor(s, off, 64);
    if (lane == 0) red[12 + j][w] = s;
  }
  __syncthreads();
  if (tid < 12){
    int j = tid % 3;
    float s  = red[tid][0] + red[tid][1] + red[tid][2] + red[tid][3];
    float bj = red[12+j][0] + red[12+j][1] + red[12+j][2] + red[12+j][3];
    out[tid] = s + bj + bp[j];
  }
}

extern "C" void kernel_launch(void* const* d_in, const int* in_sizes, int n_in,
                              void* d_out, int out_size, void* d_ws, size_t ws_size,
                              hipStream_t stream) {
  const int M = BB * SS;                      // 8192
  const int* ids  = (const int*)d_in[0];
  const int* mask = (const int*)d_in[1];
  const float* emb = (const float*)d_in[2];
  const float* Wq = (const float*)d_in[3];  const float* bq = (const float*)d_in[4];
  const float* Wk = (const float*)d_in[5];  const float* bk = (const float*)d_in[6];
  const float* Wv = (const float*)d_in[7];  const float* bv = (const float*)d_in[8];
  const float* Wo = (const float*)d_in[9];  const float* bo = (const float*)d_in[10];
  const float* lg = (const float*)d_in[11]; const float* lb = (const float*)d_in[12];
  const float* W1 = (const float*)d_in[13]; const float* b1 = (const float*)d_in[14];
  const float* W2 = (const float*)d_in[15]; const float* b2 = (const float*)d_in[16];
  const float* Wp = (const float*)d_in[17]; const float* bp = (const float*)d_in[18];

  // workspace layout (bytes), all offsets 16B-aligned
  char* base = (char*)d_ws;
  const size_t SLOTF = (size_t)M * EE;        // elements per [M,E] matrix
  float* xf   = (float*)base;                          // f32   33.55 MB
  u16*  xbf   = (u16*)(base + SLOTF*4);                // bf16  16.78 MB
  u16*  qbf   = (u16*)(base + SLOTF*6);                // q,k,v contiguous (QKV-fused epilogue)
  u16*  kbf   = (u16*)(base + SLOTF*8);
  u16*  vbf   = (u16*)(base + SLOTF*10);
  u16*  ctxbf = (u16*)(base + SLOTF*12);
  u16*  c2bf  = qbf;                                   // q dead after attention
  u16*  hbf   = kbf;                                   // k dead after attention
  u16*  WqT   = (u16*)(base + SLOTF*14);               // WqT/WkT/WvT contiguous [3072][1024]
  u16*  WkT   = WqT + (size_t)EE*EE;
  u16*  WvT   = WkT + (size_t)EE*EE;
  u16*  WoT   = WvT + (size_t)EE*EE;
  u16*  W1T   = WoT + (size_t)EE*EE;                   // [F][E] bf16, 8 MB
  float* gsum = (float*)(W1T + (size_t)FF*EE);         // [B][F]
  float* w2wp = gsum + BB*FF;                          // [F][3]

  hipMemsetAsync(gsum, 0, BB*FF*sizeof(float), stream);

  embed_kernel<<<M, 256, 0, stream>>>(ids, emb, xf, xbf);

  transpose_bf16<<<dim3(EE/32, EE/32), 256, 0, stream>>>(Wq, WqT, EE, EE);
  transpose_bf16<<<dim3(EE/32, EE/32), 256, 0, stream>>>(Wk, WkT, EE, EE);
  transpose_bf16<<<dim3(EE/32, EE/32), 256, 0, stream>>>(Wv, WvT, EE, EE);
  transpose_bf16<<<dim3(EE/32, EE/32), 256, 0, stream>>>(Wo, WoT, EE, EE);
  transpose_bf16<<<dim3(FF/32, EE/32), 256, 0, stream>>>(W1, W1T, EE, FF);
  w2wp_kernel<<<FF/8, 256, 0, stream>>>(W2, Wp, w2wp);

  // fused QKV: one dispatch, 1536 blocks (~6/CU) instead of 3 x 512 (2/CU)
  gemm_mfma<2><<<dim3(3*EE/128, M/128), 256, 0, stream>>>(
      xbf, WqT, bq, bk, bv, qbf, nullptr, M, EE, EE);

  attn_mfma<<<dim3(SS/128, BB*HH), 512, 0, stream>>>(qbf, kbf, vbf, mask, ctxbf);

  gemm_mfma<0><<<dim3(EE/128, M/128), 256, 0, stream>>>(
      ctxbf, WoT, bo, nullptr, nullptr, c2bf, nullptr, M, EE, EE);

  ln_kernel<<<M, 256, 0, stream>>>(c2bf, xf, lg, lb, hbf);

  gemm_mfma<1><<<dim3(FF/128, M/128), 256, 0, stream>>>(
      hbf, W1T, b1, nullptr, nullptr, nullptr, gsum, M, FF, EE);

  out_final<<<1, 256, 0, stream>>>(gsum, w2wp, b2, Wp, bp, (float*)d_out);
}

// Round 5
// 624.986 us; speedup vs baseline: 7.9876x; 1.0345x over previous
//
#include <hip/hip_runtime.h>
#include <hip/hip_bf16.h>
#include <math.h>

// Problem constants
#define BB 4
#define SS 2048
#define EE 1024
#define HH 16
#define DD 64
#define FF 4096

typedef unsigned short u16;
typedef unsigned int u32;
typedef __bf16 bf16x8 __attribute__((ext_vector_type(8)));
typedef float f32x4 __attribute__((ext_vector_type(4)));

static __device__ __forceinline__ float gelu_exact(float v){
  return 0.5f * v * (1.0f + erff(v * 0.70710678118654752f));
}

// float -> bf16 (RNE)
static __device__ __forceinline__ u16 f2bf(float f){
  union { float f; u32 u; } x; x.f = f;
  u32 r = x.u + 0x7FFFu + ((x.u >> 16) & 1u);
  return (u16)(r >> 16);
}
// unpack a u32 holding two bf16 (little-endian: elem0 = low half)
static __device__ __forceinline__ void unpack2(u32 u, float& lo, float& hi){
  union { u32 u; float f; } a, b;
  a.u = u << 16; b.u = u & 0xFFFF0000u;
  lo = a.f; hi = b.f;
}

#define GLOAD_LDS16(g, l) \
  __builtin_amdgcn_global_load_lds((const __attribute__((address_space(1))) void*)(g), \
      (__attribute__((address_space(3))) void*)(l), 16, 0, 0)

// ---------------- embedding gather: write f32 (for residual) + bf16 (GEMM A) ----------------
__global__ __launch_bounds__(256) void embed_kernel(const int* __restrict__ ids,
    const float* __restrict__ emb, float* __restrict__ xf, u16* __restrict__ xbf){
  int row = blockIdx.x;
  int id  = ids[row];
  float4 v = ((const float4*)(emb + (size_t)id * EE))[threadIdx.x];
  ((float4*)(xf + (size_t)row * EE))[threadIdx.x] = v;
  ushort4 u; u.x = f2bf(v.x); u.y = f2bf(v.y); u.z = f2bf(v.z); u.w = f2bf(v.w);
  ((ushort4*)(xbf + (size_t)row * EE))[threadIdx.x] = u;
}

// ---------------- fused weight prep: all 5 transposes in one dispatch ----------------
// WT base layout: WqT,WkT,WvT,WoT (each [EE][EE]) then W1T ([FF][EE]), contiguous.
// Blocks 0..4095: W1 tiles (N=FF, 128 x 32 tiles). Blocks 4096..8191: Wq/Wk/Wv/Wo.
__global__ __launch_bounds__(256) void prep_weights(const float* __restrict__ Wq,
    const float* __restrict__ Wk, const float* __restrict__ Wv,
    const float* __restrict__ Wo, const float* __restrict__ W1, u16* __restrict__ WT){
  __shared__ float tile[32][33];
  int bid = blockIdx.x;
  const float* W; u16* dst; int N, n0, k0;
  if (bid < 4096){
    W = W1; dst = WT + (size_t)4 * EE * EE; N = FF;
    n0 = (bid & 127) * 32; k0 = (bid >> 7) * 32;
  } else {
    int idx = bid - 4096;
    int which = idx >> 10, t = idx & 1023;
    W = (which == 0) ? Wq : (which == 1) ? Wk : (which == 2) ? Wv : Wo;
    dst = WT + (size_t)which * EE * EE; N = EE;
    n0 = (t & 31) * 32; k0 = (t >> 5) * 32;
  }
  int tx = threadIdx.x & 31, ty = threadIdx.x >> 5;   // ty 0..7
  #pragma unroll
  for (int i = 0; i < 4; i++)
    tile[ty + 8*i][tx] = W[(size_t)(k0 + ty + 8*i) * N + n0 + tx];
  __syncthreads();
  #pragma unroll
  for (int i = 0; i < 4; i++)
    dst[(size_t)(n0 + ty + 8*i) * EE + k0 + tx] = f2bf(tile[tx][ty + 8*i]);
}

// ---------------- bf16 MFMA GEMM: C[M,N] = A[M,K] @ W[K,N] + bias ----------------
// A: bf16 row-major [M,K]. WT: bf16 [N,K] (W transposed). 128x128 tile, BK=32.
// MODE 0: store bf16 C.
// MODE 1: gelu + per-batch column-sum atomics into gsum[B][N].
// MODE 2: fused QKV: WT spans 3*N rows; output slab sel = col>>10 into C + sel*M*N,
//         bias selected from {bias, biasB, biasC}.
template<int MODE>
__global__ __launch_bounds__(256) void gemm_mfma(const u16* __restrict__ A,
    const u16* __restrict__ WT, const float* __restrict__ bias,
    const float* __restrict__ biasB, const float* __restrict__ biasC,
    u16* __restrict__ C, float* __restrict__ gsum, int M, int N, int K){
  __shared__ __attribute__((aligned(16))) u16 As[128 * 32];   // [row][k] 8 KB
  __shared__ __attribute__((aligned(16))) u16 Bs[128 * 32];   // [n][k]   8 KB

  const int tid = threadIdx.x;
  const int l = tid & 63, w = tid >> 6;
  const int lm = l & 15, lq = l >> 4;
  const int wm = (w >> 1) * 64, wn = (w & 1) * 64;
  const int r0 = blockIdx.y * 128, c0 = blockIdx.x * 128;

  const int srow0 = w * 32 + (l >> 2);          // row for instr 0
  const int scol  = (l & 3) * 8;                // k-element offset within row
  const u16* Ab = A  + (size_t)(r0 + srow0) * K + scol;
  const u16* Bb = WT + (size_t)(c0 + srow0) * K + scol;
  u16* AsBase0 = &As[(w * 2)     * 512];
  u16* AsBase1 = &As[(w * 2 + 1) * 512];
  u16* BsBase0 = &Bs[(w * 2)     * 512];
  u16* BsBase1 = &Bs[(w * 2 + 1) * 512];

  f32x4 acc[4][4];
  const f32x4 zero = {0.f, 0.f, 0.f, 0.f};
  #pragma unroll
  for (int mi = 0; mi < 4; mi++)
    #pragma unroll
    for (int ni = 0; ni < 4; ni++) acc[mi][ni] = zero;

  for (int k0 = 0; k0 < K; k0 += 32){
    GLOAD_LDS16(Ab + k0,                    AsBase0);
    GLOAD_LDS16(Ab + (size_t)16 * K + k0,   AsBase1);
    GLOAD_LDS16(Bb + k0,                    BsBase0);
    GLOAD_LDS16(Bb + (size_t)16 * K + k0,   BsBase1);
    __syncthreads();

    bf16x8 af[4], bf[4];
    #pragma unroll
    for (int mi = 0; mi < 4; mi++)
      af[mi] = *(const bf16x8*)&As[(wm + mi*16 + lm) * 32 + lq * 8];
    #pragma unroll
    for (int ni = 0; ni < 4; ni++)
      bf[ni] = *(const bf16x8*)&Bs[(wn + ni*16 + lm) * 32 + lq * 8];
    #pragma unroll
    for (int mi = 0; mi < 4; mi++)
      #pragma unroll
      for (int ni = 0; ni < 4; ni++)
        acc[mi][ni] = __builtin_amdgcn_mfma_f32_16x16x32_bf16(af[mi], bf[ni], acc[mi][ni], 0, 0, 0);
    __syncthreads();
  }

  // C/D layout (verified m89/m91): col = lane&15, row = (lane>>4)*4 + reg
  if constexpr (MODE == 0){
    #pragma unroll
    for (int ni = 0; ni < 4; ni++){
      int col = c0 + wn + ni*16 + lm;
      float bcol = bias[col];
      #pragma unroll
      for (int mi = 0; mi < 4; mi++){
        #pragma unroll
        for (int r = 0; r < 4; r++){
          int row = r0 + wm + mi*16 + lq*4 + r;
          C[(size_t)row * N + col] = f2bf(acc[mi][ni][r] + bcol);
        }
      }
    }
  } else if constexpr (MODE == 2){
    #pragma unroll
    for (int ni = 0; ni < 4; ni++){
      int col3 = c0 + wn + ni*16 + lm;      // never crosses a 1024 boundary within 16
      int sel  = col3 >> 10;
      int colm = col3 & 1023;
      const float* bp_ = (sel == 0) ? bias : ((sel == 1) ? biasB : biasC);
      float bcol = bp_[colm];
      u16* dst = C + (size_t)sel * ((size_t)M * N);
      #pragma unroll
      for (int mi = 0; mi < 4; mi++){
        #pragma unroll
        for (int r = 0; r < 4; r++){
          int row = r0 + wm + mi*16 + lq*4 + r;
          dst[(size_t)row * N + colm] = f2bf(acc[mi][ni][r] + bcol);
        }
      }
    }
  } else {
    const int batch = r0 >> 11;   // 2048 rows per batch, 128 | 2048
    #pragma unroll
    for (int ni = 0; ni < 4; ni++){
      int col = c0 + wn + ni*16 + lm;
      float bcol = bias[col];
      float cs = 0.f;
      #pragma unroll
      for (int mi = 0; mi < 4; mi++)
        #pragma unroll
        for (int r = 0; r < 4; r++)
          cs += gelu_exact(acc[mi][ni][r] + bcol);
      cs += __shfl_xor(cs, 16, 64);
      cs += __shfl_xor(cs, 32, 64);
      if (lq == 0) atomicAdd(&gsum[(size_t)batch * N + col], cs);
    }
  }
}

// ---------------- MFMA flash attention, bf16, no-max softmax, 32 q-rows/wave ----------------
// Block: one (b,h), 128 q-rows; 4 waves x 32 q-rows; 256 threads. K-tiles of 64 keys.
// LDS-port-bound analysis (r4): K/V-tile reads are fixed per wave per tile, so 32
// q-rows/wave halves LDS reads per unit work. Register-buffered prefetch: next
// tile's K/V global loads issue right after the barrier and land during compute.
// exp2-domain softmax (v_exp_f32 is natively 2^x). V staged transposed with
// packed b32 key-pair writes. No max-subtraction (scores O(1e-3); clamp guards).
__global__ __launch_bounds__(256, 4) void attn_mfma(const u16* __restrict__ q,
    const u16* __restrict__ k, const u16* __restrict__ v,
    const int* __restrict__ mask, u16* __restrict__ ctx){
  const int bh = blockIdx.y, b = bh >> 4, h = bh & 15;
  const int q0 = blockIdx.x * 128;
  const int tid = threadIdx.x;
  const int w = tid >> 6, l = tid & 63, lm = l & 15, lq = l >> 4;

  __shared__ __attribute__((aligned(16))) u16 Kt[64 * 72];
  __shared__ __attribute__((aligned(16))) u16 Vt[64 * 72];
  __shared__ __attribute__((aligned(16))) u16 Pw[4][32 * 72];
  __shared__ float mb[64];

  // Q A-frags direct from global: A[m=lane&15][k=quad*8+j]; 2 row-groups per wave
  bf16x8 aq[2][2];
  #pragma unroll
  for (int mg = 0; mg < 2; mg++){
    const u16* qrow = q + (size_t)(b*SS + q0 + w*32 + mg*16 + lm) * EE + h*DD + lq*8;
    aq[mg][0] = *(const bf16x8*)qrow;
    aq[mg][1] = *(const bf16x8*)(qrow + 32);
  }

  f32x4 occ[2][4];
  const f32x4 zero = {0.f,0.f,0.f,0.f};
  #pragma unroll
  for (int mg = 0; mg < 2; mg++)
    #pragma unroll
    for (int ni = 0; ni < 4; ni++) occ[mg][ni] = zero;
  float l_part[2][4] = {{0.f,0.f,0.f,0.f},{0.f,0.f,0.f,0.f}};

  // staging coords: K natural [key][d] (4 thr/key, 32B each); V key-pairs
  const int kkey = tid >> 2, kc16 = (tid & 3) * 16;
  const u16* kbase = k + (size_t)(b*SS + kkey) * EE + h*DD + kc16;
  const int kp = tid & 31, vd0 = (tid >> 5) * 8;
  const u16* vbase0 = v + (size_t)(b*SS + 2*kp) * EE + h*DD + vd0;
  const u16* vbase1 = vbase0 + EE;

  // prefetch tile 0 into registers
  uint4 kr0 = *(const uint4*)(kbase);
  uint4 kr1 = *(const uint4*)(kbase + 8);
  uint4 vr0 = *(const uint4*)(vbase0);
  uint4 vr1 = *(const uint4*)(vbase1);
  float mreg = 0.f;
  if (tid < 64) mreg = (mask[b*SS + tid] != 0) ? 0.f : -1e30f;

  const float SCALE_LOG2E = 0.125f * 1.4426950408889634f;

  for (int t0 = 0; t0 < SS; t0 += 64){
    // commit staged registers to LDS
    *(uint4*)&Kt[kkey*72 + kc16]     = kr0;
    *(uint4*)&Kt[kkey*72 + kc16 + 8] = kr1;
    {
      union { uint4 u; u16 s[8]; } va, vb;
      va.u = vr0; vb.u = vr1;
      #pragma unroll
      for (int i = 0; i < 8; i++){
        u32 pk = (u32)va.s[i] | ((u32)vb.s[i] << 16);
        *(u32*)&Vt[(vd0 + i)*72 + 2*kp] = pk;
      }
    }
    if (tid < 64) mb[tid] = mreg;
    __syncthreads();

    // prefetch next tile (lands during compute below)
    if (t0 + 64 < SS){
      kr0 = *(const uint4*)(kbase + (size_t)(t0 + 64) * EE);
      kr1 = *(const uint4*)(kbase + (size_t)(t0 + 64) * EE + 8);
      vr0 = *(const uint4*)(vbase0 + (size_t)(t0 + 64) * EE);
      vr1 = *(const uint4*)(vbase1 + (size_t)(t0 + 64) * EE);
      if (tid < 64) mreg = (mask[b*SS + t0 + 64 + tid] != 0) ? 0.f : -1e30f;
    }

    // QK^T + softmax + P-write, one row-group at a time (caps live sc regs)
    #pragma unroll
    for (int mg = 0; mg < 2; mg++){
      #pragma unroll
      for (int ni = 0; ni < 4; ni++){
        bf16x8 b0 = *(const bf16x8*)&Kt[(ni*16 + lm)*72 + lq*8];
        bf16x8 b1 = *(const bf16x8*)&Kt[(ni*16 + lm)*72 + 32 + lq*8];
        f32x4 sc = zero;
        sc = __builtin_amdgcn_mfma_f32_16x16x32_bf16(aq[mg][0], b0, sc, 0, 0, 0);
        sc = __builtin_amdgcn_mfma_f32_16x16x32_bf16(aq[mg][1], b1, sc, 0, 0, 0);
        float mbias = mb[ni*16 + lm];
        #pragma unroll
        for (int r = 0; r < 4; r++){
          float s = fminf(fmaf(sc[r], SCALE_LOG2E, mbias), 80.f);
          float p = __builtin_amdgcn_exp2f(s);
          l_part[mg][r] += p;
          Pw[w][(mg*16 + lq*4 + r)*72 + ni*16 + lm] = f2bf(p);
        }
      }
    }
    // P: C-layout -> A-layout via wave-private LDS (no barrier needed)
    bf16x8 ap[2][2];
    #pragma unroll
    for (int mg = 0; mg < 2; mg++){
      ap[mg][0] = *(const bf16x8*)&Pw[w][(mg*16 + lm)*72 + lq*8];
      ap[mg][1] = *(const bf16x8*)&Pw[w][(mg*16 + lm)*72 + 32 + lq*8];
    }

    // PV: B-frags from Vt[d][key] shared across both row-groups
    #pragma unroll
    for (int ni = 0; ni < 4; ni++){
      bf16x8 vb0 = *(const bf16x8*)&Vt[(ni*16 + lm)*72 + lq*8];
      bf16x8 vb1 = *(const bf16x8*)&Vt[(ni*16 + lm)*72 + 32 + lq*8];
      #pragma unroll
      for (int mg = 0; mg < 2; mg++){
        occ[mg][ni] = __builtin_amdgcn_mfma_f32_16x16x32_bf16(ap[mg][0], vb0, occ[mg][ni], 0, 0, 0);
        occ[mg][ni] = __builtin_amdgcn_mfma_f32_16x16x32_bf16(ap[mg][1], vb1, occ[mg][ni], 0, 0, 0);
      }
    }
    __syncthreads();
  }

  // final l reduction across the 16-lane column group, once
  #pragma unroll
  for (int mg = 0; mg < 2; mg++){
    float inv[4];
    #pragma unroll
    for (int r = 0; r < 4; r++){
      float s = l_part[mg][r];
      s += __shfl_xor(s, 1, 64);
      s += __shfl_xor(s, 2, 64);
      s += __shfl_xor(s, 4, 64);
      s += __shfl_xor(s, 8, 64);
      inv[r] = 1.f / s;
    }
    #pragma unroll
    for (int ni = 0; ni < 4; ni++){
      int col = h*DD + ni*16 + lm;
      #pragma unroll
      for (int r = 0; r < 4; r++){
        int row = q0 + w*32 + mg*16 + lq*4 + r;
        ctx[(size_t)(b*SS + row) * EE + col] = f2bf(occ[mg][ni][r] * inv[r]);
      }
    }
  }
}

// ---------------- fused residual + LayerNorm (bf16 ctx2 in, bf16 h out) ----------------
__global__ __launch_bounds__(256) void ln_kernel(const u16* __restrict__ c2,
    const float* __restrict__ x, const float* __restrict__ g,
    const float* __restrict__ bta, u16* __restrict__ h){
  int row = blockIdx.x, tid = threadIdx.x;
  uint2 cu = ((const uint2*)(c2 + (size_t)row * EE))[tid];
  float c0,c1,c2f,c3;
  unpack2(cu.x, c0, c1); unpack2(cu.y, c2f, c3);
  float4 xv = ((const float4*)(x + (size_t)row * EE))[tid];
  float4 y = make_float4(c0+xv.x, c1+xv.y, c2f+xv.z, c3+xv.w);
  float s  = y.x + y.y + y.z + y.w;
  float ss = y.x*y.x + y.y*y.y + y.z*y.z + y.w*y.w;
  #pragma unroll
  for (int off=32; off; off>>=1){
    s  += __shfl_xor(s,  off, 64);
    ss += __shfl_xor(ss, off, 64);
  }
  __shared__ float rs[4], rss[4];
  int w = tid >> 6;
  if ((tid & 63) == 0){ rs[w] = s; rss[w] = ss; }
  __syncthreads();
  float tot  = rs[0]+rs[1]+rs[2]+rs[3];
  float tots = rss[0]+rss[1]+rss[2]+rss[3];
  float mu  = tot  * (1.f/EE);
  float var = tots * (1.f/EE) - mu*mu;
  float inv = rsqrtf(var + 1e-5f);
  float4 gv = ((const float4*)g)[tid];
  float4 bv = ((const float4*)bta)[tid];
  ushort4 ou;
  ou.x = f2bf((y.x-mu)*inv*gv.x + bv.x);
  ou.y = f2bf((y.y-mu)*inv*gv.y + bv.y);
  ou.z = f2bf((y.z-mu)*inv*gv.z + bv.z);
  ou.w = f2bf((y.w-mu)*inv*gv.w + bv.w);
  ((ushort4*)(h + (size_t)row * EE))[tid] = ou;
}

// ---------------- W2Wp[f][j] = sum_e W2[f][e] * Wp[e][j] ----------------
__global__ __launch_bounds__(256) void w2wp_kernel(const float* __restrict__ W2,
    const float* __restrict__ Wp, float* __restrict__ W2Wp){
  int f0 = blockIdx.x * 8;
  int tid = threadIdx.x;
  int e0 = tid * 4;
  float wp[4][3];
  #pragma unroll
  for (int t = 0; t < 4; t++)
    #pragma unroll
    for (int j = 0; j < 3; j++) wp[t][j] = Wp[(e0 + t)*3 + j];
  __shared__ float red[3][4];
  for (int i = 0; i < 8; i++){
    int f = f0 + i;
    float4 wv = ((const float4*)(W2 + (size_t)f * EE))[tid];
    float w4[4] = {wv.x, wv.y, wv.z, wv.w};
    float p[3] = {0.f, 0.f, 0.f};
    #pragma unroll
    for (int t = 0; t < 4; t++)
      #pragma unroll
      for (int j = 0; j < 3; j++) p[j] += w4[t] * wp[t][j];
    #pragma unroll
    for (int j = 0; j < 3; j++){
      float sj = p[j];
      #pragma unroll
      for (int off = 32; off; off >>= 1) sj += __shfl_xor(sj, off, 64);
      if ((tid & 63) == 0) red[j][tid >> 6] = sj;
    }
    __syncthreads();
    if (tid < 3) W2Wp[f*3 + tid] = red[tid][0] + red[tid][1] + red[tid][2] + red[tid][3];
    __syncthreads();
  }
}

// ---------------- out[b,j] = sum_f (gsum[b,f]/S) W2Wp[f,j] + (b2@Wp)[j] + bp[j] ----------------
__global__ __launch_bounds__(256) void out_final(const float* __restrict__ gsum,
    const float* __restrict__ W2Wp, const float* __restrict__ b2,
    const float* __restrict__ Wp, const float* __restrict__ bp, float* __restrict__ out){
  int tid = threadIdx.x;
  float part[4][3];
  #pragma unroll
  for (int b = 0; b < 4; b++)
    #pragma unroll
    for (int j = 0; j < 3; j++) part[b][j] = 0.f;
  for (int f = tid; f < FF; f += 256){
    float w0 = W2Wp[f*3], w1 = W2Wp[f*3+1], w2v = W2Wp[f*3+2];
    #pragma unroll
    for (int b = 0; b < 4; b++){
      float g = gsum[b*FF + f] * (1.f/SS);
      part[b][0] += g * w0; part[b][1] += g * w1; part[b][2] += g * w2v;
    }
  }
  float bb[3] = {0.f, 0.f, 0.f};
  for (int e = tid; e < EE; e += 256){
    float bv = b2[e];
    bb[0] += bv * Wp[e*3]; bb[1] += bv * Wp[e*3+1]; bb[2] += bv * Wp[e*3+2];
  }
  __shared__ float red[15][4];
  int lane = tid & 63, w = tid >> 6;
  #pragma unroll
  for (int b = 0; b < 4; b++)
    #pragma unroll
    for (int j = 0; j < 3; j++){
      float s = part[b][j];
      #pragma unroll
      for (int off = 32; off; off >>= 1) s += __shfl_xor(s, off, 64);
      if (lane == 0) red[b*3 + j][w] = s;
    }
  #pragma unroll
  for (int j = 0; j < 3; j++){
    float s = bb[j];
    #pragma unroll
    for (int off = 32; off; off >>= 1) s += __shfl_xor(s, off, 64);
    if (lane == 0) red[12 + j][w] = s;
  }
  __syncthreads();
  if (tid < 12){
    int j = tid % 3;
    float s  = red[tid][0] + red[tid][1] + red[tid][2] + red[tid][3];
    float bj = red[12+j][0] + red[12+j][1] + red[12+j][2] + red[12+j][3];
    out[tid] = s + bj + bp[j];
  }
}

extern "C" void kernel_launch(void* const* d_in, const int* in_sizes, int n_in,
                              void* d_out, int out_size, void* d_ws, size_t ws_size,
                              hipStream_t stream) {
  const int M = BB * SS;                      // 8192
  const int* ids  = (const int*)d_in[0];
  const int* mask = (const int*)d_in[1];
  const float* emb = (const float*)d_in[2];
  const float* Wq = (const float*)d_in[3];  const float* bq = (const float*)d_in[4];
  const float* Wk = (const float*)d_in[5];  const float* bk = (const float*)d_in[6];
  const float* Wv = (const float*)d_in[7];  const float* bv = (const float*)d_in[8];
  const float* Wo = (const float*)d_in[9];  const float* bo = (const float*)d_in[10];
  const float* lg = (const float*)d_in[11]; const float* lb = (const float*)d_in[12];
  const float* W1 = (const float*)d_in[13]; const float* b1 = (const float*)d_in[14];
  const float* W2 = (const float*)d_in[15]; const float* b2 = (const float*)d_in[16];
  const float* Wp = (const float*)d_in[17]; const float* bp = (const float*)d_in[18];

  // workspace layout (bytes), all offsets 16B-aligned
  char* base = (char*)d_ws;
  const size_t SLOTF = (size_t)M * EE;        // elements per [M,E] matrix
  float* xf   = (float*)base;                          // f32   33.55 MB
  u16*  xbf   = (u16*)(base + SLOTF*4);                // bf16  16.78 MB
  u16*  qbf   = (u16*)(base + SLOTF*6);                // q,k,v contiguous (QKV-fused epilogue)
  u16*  kbf   = (u16*)(base + SLOTF*8);
  u16*  vbf   = (u16*)(base + SLOTF*10);
  u16*  ctxbf = (u16*)(base + SLOTF*12);
  u16*  c2bf  = qbf;                                   // q dead after attention
  u16*  hbf   = kbf;                                   // k dead after attention
  u16*  WqT   = (u16*)(base + SLOTF*14);               // WqT/WkT/WvT/WoT/W1T contiguous
  u16*  W1T   = WqT + (size_t)4*EE*EE;
  float* gsum = (float*)(W1T + (size_t)FF*EE);         // [B][F]
  float* w2wp = gsum + BB*FF;                          // [F][3]

  hipMemsetAsync(gsum, 0, BB*FF*sizeof(float), stream);

  embed_kernel<<<M, 256, 0, stream>>>(ids, emb, xf, xbf);

  prep_weights<<<8192, 256, 0, stream>>>(Wq, Wk, Wv, Wo, W1, WqT);
  w2wp_kernel<<<FF/8, 256, 0, stream>>>(W2, Wp, w2wp);

  // fused QKV: one dispatch, 1536 blocks
  gemm_mfma<2><<<dim3(3*EE/128, M/128), 256, 0, stream>>>(
      xbf, WqT, bq, bk, bv, qbf, nullptr, M, EE, EE);

  attn_mfma<<<dim3(SS/128, BB*HH), 256, 0, stream>>>(qbf, kbf, vbf, mask, ctxbf);

  gemm_mfma<0><<<dim3(EE/128, M/128), 256, 0, stream>>>(
      ctxbf, WqT + (size_t)3*EE*EE, bo, nullptr, nullptr, c2bf, nullptr, M, EE, EE);

  ln_kernel<<<M, 256, 0, stream>>>(c2bf, xf, lg, lb, hbf);

  gemm_mfma<1><<<dim3(FF/128, M/128), 256, 0, stream>>>(
      hbf, W1T, b1, nullptr, nullptr, nullptr, gsum, M, FF, EE);

  out_final<<<1, 256, 0, stream>>>(gsum, w2wp, b2, Wp, bp, (float*)d_out);
}